// Round 1
// baseline (3953.426 us; speedup 1.0000x reference)
//
#include <hip/hip_runtime.h>

#define NN 50000
#define NE 800000
#define NG 256

// ---------- helpers ----------
__device__ __forceinline__ unsigned fkey(float f) {
    unsigned u = __float_as_uint(f);
    return (u & 0x80000000u) ? ~u : (u | 0x80000000u);
}
__device__ __forceinline__ float funkey(unsigned k) {
    unsigned u = (k & 0x80000000u) ? (k ^ 0x80000000u) : ~k;
    return __uint_as_float(u);
}

// ---------- kernels ----------
__global__ void copy_f4(const float4* __restrict__ src, float4* __restrict__ dst, int n4) {
    int i = blockIdx.x * blockDim.x + threadIdx.x;
    if (i < n4) dst[i] = src[i];
}

// one thread per (edge, 4-feature chunk); chunks = din/4 = 1<<cshift
__global__ void scatter_add(const float* __restrict__ x, const int* __restrict__ src,
                            const int* __restrict__ dst, float* __restrict__ agg,
                            int din, int cshift) {
    int t = blockIdx.x * blockDim.x + threadIdx.x;
    int e = t >> cshift;
    if (e >= NE) return;
    int c = t & ((1 << cshift) - 1);
    int s = src[e], d = dst[e];
    float4 v = *(const float4*)(x + (size_t)s * din + c * 4);
    float* ap = agg + (size_t)d * din + c * 4;
    atomicAdd(ap + 0, v.x);
    atomicAdd(ap + 1, v.y);
    atomicAdd(ap + 2, v.z);
    atomicAdd(ap + 3, v.w);
}

// block = (DOUT, NPB) threads; per node: z = relu(h@W1+b1)@W2+b2, BN, optional relu
template <int DIN, int DOUT>
__global__ void mlp_bn(const float* __restrict__ agg, float* __restrict__ out,
                       const float* __restrict__ W1, const float* __restrict__ b1,
                       const float* __restrict__ W2, const float* __restrict__ b2,
                       const float* __restrict__ gamma, const float* __restrict__ beta,
                       const float* __restrict__ mean, const float* __restrict__ var,
                       int relu_out) {
    constexpr int NPB = 256 / DOUT;
    __shared__ float sh[NPB][DIN];
    __shared__ float sy[NPB][DOUT];
    int j  = threadIdx.x;   // output feature
    int yi = threadIdx.y;   // node slot within block
    int node = blockIdx.x * NPB + yi;

    if (node < NN) {
        for (int k = j; k < DIN; k += DOUT)
            sh[yi][k] = agg[(size_t)node * DIN + k];
    }
    __syncthreads();

    float acc1 = 0.f;
    if (node < NN) {
        acc1 = b1[j];
        #pragma unroll 8
        for (int k = 0; k < DIN; k++)
            acc1 = fmaf(sh[yi][k], W1[k * DOUT + j], acc1);
        acc1 = fmaxf(acc1, 0.f);
        sy[yi][j] = acc1;
    }
    __syncthreads();

    if (node < NN) {
        float acc = b2[j];
        #pragma unroll 8
        for (int k = 0; k < DOUT; k++)
            acc = fmaf(sy[yi][k], W2[k * DOUT + j], acc);
        float inv = 1.0f / sqrtf(var[j] + 1e-5f);
        acc = (acc - mean[j]) * inv * gamma[j] + beta[j];
        if (relu_out) acc = fmaxf(acc, 0.f);
        out[(size_t)node * DOUT + j] = acc;
    }
}

__global__ void logits_kernel(const float* __restrict__ x, const float* __restrict__ Wl,
                              const float* __restrict__ bl, float* __restrict__ logits) {
    int n = blockIdx.x * blockDim.x + threadIdx.x;
    if (n >= NN) return;
    float acc = bl[0];
    #pragma unroll
    for (int k = 0; k < 32; k++)
        acc = fmaf(x[(size_t)n * 32 + k], Wl[k], acc);
    logits[n] = acc * 0.2f;  // / TEMP (5.0)
}

__global__ void init_gm(unsigned* __restrict__ gmax, float* __restrict__ gsum) {
    int g = threadIdx.x;
    if (g < NG) { gmax[g] = 0u; gsum[g] = 0.f; }
}

__global__ void seg_max(const float* __restrict__ logits, const int* __restrict__ batch,
                        unsigned* __restrict__ gmax) {
    int n = blockIdx.x * blockDim.x + threadIdx.x;
    if (n >= NN) return;
    atomicMax(&gmax[batch[n]], fkey(logits[n]));
}

__global__ void seg_expsum(const float* __restrict__ logits, const int* __restrict__ batch,
                           const unsigned* __restrict__ gmax, float* __restrict__ e_out,
                           float* __restrict__ gsum) {
    int n = blockIdx.x * blockDim.x + threadIdx.x;
    if (n >= NN) return;
    int g = batch[n];
    float e = __expf(0.f);  // placeholder avoided; use expf below
    e = expf(logits[n] - funkey(gmax[g]));
    e_out[n] = e;
    atomicAdd(&gsum[g], e);
}

__global__ void seg_div(float* __restrict__ out, const int* __restrict__ batch,
                        const float* __restrict__ gsum) {
    int n = blockIdx.x * blockDim.x + threadIdx.x;
    if (n >= NN) return;
    out[n] = out[n] / gsum[batch[n]];
}

// ---------- launch ----------
extern "C" void kernel_launch(void* const* d_in, const int* in_sizes, int n_in,
                              void* d_out, int out_size, void* d_ws, size_t ws_size,
                              hipStream_t stream) {
    const float* x    = (const float*)d_in[0];
    const int*   ei   = (const int*)d_in[1];
    const int*   srcI = ei;
    const int*   dstI = ei + NE;
    const int*   batch = (const int*)d_in[2];

    const float* P[29];
    for (int i = 0; i < 29; i++) P[i] = (const float*)d_in[i];
    // layer i params at 3 + 8*i: W1,b1,W2,b2,gamma,beta,mean,var
    const float* Wlin = P[27];
    const float* blin = P[28];

    float* bufA = (float*)d_ws;             // N x 128 (agg)
    float* bufB = bufA + (size_t)NN * 128;  // N x 128 (layer out)
    float* logits = bufB + (size_t)NN * 128;
    unsigned* gmax = (unsigned*)(logits + NN);
    float* gsum = (float*)(gmax + NG);
    float* outp = (float*)d_out;

    const int TB = 256;

    // ---- layer 0: din=128, dout=128, relu ----
    {
        int n4 = NN * 128 / 4;
        copy_f4<<<(n4 + TB - 1) / TB, TB, 0, stream>>>((const float4*)x, (float4*)bufA, n4);
        int total = NE * 32;  // din/4 = 32 chunks
        scatter_add<<<(total + TB - 1) / TB, TB, 0, stream>>>(x, srcI, dstI, bufA, 128, 5);
        mlp_bn<128, 128><<<(NN + 1) / 2, dim3(128, 2), 0, stream>>>(
            bufA, bufB, P[3], P[4], P[5], P[6], P[7], P[8], P[9], P[10], 1);
    }
    // ---- layer 1: din=128, dout=64, relu ----
    {
        int n4 = NN * 128 / 4;
        copy_f4<<<(n4 + TB - 1) / TB, TB, 0, stream>>>((const float4*)bufB, (float4*)bufA, n4);
        int total = NE * 32;
        scatter_add<<<(total + TB - 1) / TB, TB, 0, stream>>>(bufB, srcI, dstI, bufA, 128, 5);
        mlp_bn<128, 64><<<(NN + 3) / 4, dim3(64, 4), 0, stream>>>(
            bufA, bufB, P[11], P[12], P[13], P[14], P[15], P[16], P[17], P[18], 1);
    }
    // ---- layer 2: din=64, dout=32, no relu ----
    {
        int n4 = NN * 64 / 4;
        copy_f4<<<(n4 + TB - 1) / TB, TB, 0, stream>>>((const float4*)bufB, (float4*)bufA, n4);
        int total = NE * 16;  // din/4 = 16 chunks
        scatter_add<<<(total + TB - 1) / TB, TB, 0, stream>>>(bufB, srcI, dstI, bufA, 64, 4);
        mlp_bn<64, 32><<<(NN + 7) / 8, dim3(32, 8), 0, stream>>>(
            bufA, bufB, P[19], P[20], P[21], P[22], P[23], P[24], P[25], P[26], 0);
    }

    // ---- head: logits + segment softmax ----
    logits_kernel<<<(NN + TB - 1) / TB, TB, 0, stream>>>(bufB, Wlin, blin, logits);
    init_gm<<<1, NG, 0, stream>>>(gmax, gsum);
    seg_max<<<(NN + TB - 1) / TB, TB, 0, stream>>>(logits, batch, gmax);
    seg_expsum<<<(NN + TB - 1) / TB, TB, 0, stream>>>(logits, batch, gmax, outp, gsum);
    seg_div<<<(NN + TB - 1) / TB, TB, 0, stream>>>(outp, batch, gsum);
}

// Round 2
// 994.506 us; speedup vs baseline: 3.9753x; 3.9753x over previous
//
#include <hip/hip_runtime.h>

#define NN 50000
#define NE 800000
#define NG 256

// ---------- helpers ----------
__device__ __forceinline__ unsigned fkey(float f) {
    unsigned u = __float_as_uint(f);
    return (u & 0x80000000u) ? ~u : (u | 0x80000000u);
}
__device__ __forceinline__ float funkey(unsigned k) {
    unsigned u = (k & 0x80000000u) ? (k ^ 0x80000000u) : ~k;
    return __uint_as_float(u);
}

// ---------- CSR build ----------
__global__ void hist_deg(const int* __restrict__ dst, int* __restrict__ deg) {
    int e = blockIdx.x * blockDim.x + threadIdx.x;
    if (e < NE) atomicAdd(&deg[dst[e]], 1);
}

// single block, 256 threads; chunked exclusive scan of deg[NN] -> rowptr, cur
__global__ void scan_deg(const int* __restrict__ deg, int* __restrict__ rowptr,
                         int* __restrict__ cur) {
    __shared__ int part[256];
    __shared__ int tmp[256];
    const int CH = (NN + 255) / 256;  // 196
    int t = threadIdx.x;
    int lo = t * CH, hi = min(lo + CH, NN);
    int s = 0;
    for (int i = lo; i < hi; i++) s += deg[i];
    part[t] = s;
    __syncthreads();
    // Hillis-Steele inclusive scan on part[]
    for (int off = 1; off < 256; off <<= 1) {
        int v = part[t];
        int add = (t >= off) ? part[t - off] : 0;
        __syncthreads();
        tmp[t] = v + add;
        __syncthreads();
        part[t] = tmp[t];
        __syncthreads();
    }
    int run = (t == 0) ? 0 : part[t - 1];  // exclusive base for this chunk
    for (int i = lo; i < hi; i++) {
        rowptr[i] = run;
        cur[i] = run;
        run += deg[i];
    }
    if (t == 255) rowptr[NN] = NE;
}

__global__ void fill_csr(const int* __restrict__ src, const int* __restrict__ dst,
                         int* __restrict__ cur, int* __restrict__ esrc) {
    int e = blockIdx.x * blockDim.x + threadIdx.x;
    if (e >= NE) return;
    int p = atomicAdd(&cur[dst[e]], 1);
    esrc[p] = src[e];
}

// ---------- gather aggregation: agg[n] = x[n] + sum_{e in CSR[n]} x[esrc[e]] ----------
template <int DIN>
__global__ void gather_agg(const float* __restrict__ x, const int* __restrict__ esrc,
                           const int* __restrict__ rowptr, float* __restrict__ agg) {
    int wave = threadIdx.x >> 6, lane = threadIdx.x & 63;
    int node = blockIdx.x * 4 + wave;
    if (node >= NN) return;
    int beg = rowptr[node], end = rowptr[node + 1];
    if (DIN == 128) {
        const float2* x2 = (const float2*)x;
        float2 acc = x2[(size_t)node * 64 + lane];
        for (int e = beg; e < end; e++) {
            int s = esrc[e];
            float2 v = x2[(size_t)s * 64 + lane];
            acc.x += v.x; acc.y += v.y;
        }
        ((float2*)agg)[(size_t)node * 64 + lane] = acc;
    } else {  // DIN == 64
        float acc = x[(size_t)node * 64 + lane];
        for (int e = beg; e < end; e++)
            acc += x[(size_t)esrc[e] * 64 + lane];
        agg[(size_t)node * 64 + lane] = acc;
    }
}

// ---------- MLP + BN ----------
template <int DIN, int DOUT>
__global__ void mlp_bn(const float* __restrict__ agg, float* __restrict__ out,
                       const float* __restrict__ W1, const float* __restrict__ b1,
                       const float* __restrict__ W2, const float* __restrict__ b2,
                       const float* __restrict__ gamma, const float* __restrict__ beta,
                       const float* __restrict__ mean, const float* __restrict__ var,
                       int relu_out) {
    constexpr int NPB = 256 / DOUT;
    __shared__ float sh[NPB][DIN];
    __shared__ float sy[NPB][DOUT];
    int j  = threadIdx.x;
    int yi = threadIdx.y;
    int node = blockIdx.x * NPB + yi;

    if (node < NN) {
        for (int k = j; k < DIN; k += DOUT)
            sh[yi][k] = agg[(size_t)node * DIN + k];
    }
    __syncthreads();

    if (node < NN) {
        float acc1 = b1[j];
        #pragma unroll 8
        for (int k = 0; k < DIN; k++)
            acc1 = fmaf(sh[yi][k], W1[k * DOUT + j], acc1);
        sy[yi][j] = fmaxf(acc1, 0.f);
    }
    __syncthreads();

    if (node < NN) {
        float acc = b2[j];
        #pragma unroll 8
        for (int k = 0; k < DOUT; k++)
            acc = fmaf(sy[yi][k], W2[k * DOUT + j], acc);
        float inv = 1.0f / sqrtf(var[j] + 1e-5f);
        acc = (acc - mean[j]) * inv * gamma[j] + beta[j];
        if (relu_out) acc = fmaxf(acc, 0.f);
        out[(size_t)node * DOUT + j] = acc;
    }
}

// ---------- head ----------
__global__ void logits_kernel(const float* __restrict__ x, const float* __restrict__ Wl,
                              const float* __restrict__ bl, float* __restrict__ logits) {
    int n = blockIdx.x * blockDim.x + threadIdx.x;
    if (n >= NN) return;
    float acc = bl[0];
    #pragma unroll
    for (int k = 0; k < 32; k++)
        acc = fmaf(x[(size_t)n * 32 + k], Wl[k], acc);
    logits[n] = acc * 0.2f;  // / TEMP (5.0)
}

__global__ void init_gm(unsigned* __restrict__ gmax, float* __restrict__ gsum) {
    int g = threadIdx.x;
    if (g < NG) { gmax[g] = 0u; gsum[g] = 0.f; }
}

__global__ void seg_max(const float* __restrict__ logits, const int* __restrict__ batch,
                        unsigned* __restrict__ gmax) {
    int n = blockIdx.x * blockDim.x + threadIdx.x;
    if (n >= NN) return;
    atomicMax(&gmax[batch[n]], fkey(logits[n]));
}

__global__ void seg_expsum(const float* __restrict__ logits, const int* __restrict__ batch,
                           const unsigned* __restrict__ gmax, float* __restrict__ e_out,
                           float* __restrict__ gsum) {
    int n = blockIdx.x * blockDim.x + threadIdx.x;
    if (n >= NN) return;
    int g = batch[n];
    float e = expf(logits[n] - funkey(gmax[g]));
    e_out[n] = e;
    atomicAdd(&gsum[g], e);
}

__global__ void seg_div(float* __restrict__ out, const int* __restrict__ batch,
                        const float* __restrict__ gsum) {
    int n = blockIdx.x * blockDim.x + threadIdx.x;
    if (n >= NN) return;
    out[n] = out[n] / gsum[batch[n]];
}

// ---------- launch ----------
extern "C" void kernel_launch(void* const* d_in, const int* in_sizes, int n_in,
                              void* d_out, int out_size, void* d_ws, size_t ws_size,
                              hipStream_t stream) {
    const float* x    = (const float*)d_in[0];
    const int*   ei   = (const int*)d_in[1];
    const int*   srcI = ei;
    const int*   dstI = ei + NE;
    const int*   batch = (const int*)d_in[2];

    const float* P[29];
    for (int i = 0; i < 29; i++) P[i] = (const float*)d_in[i];
    const float* Wlin = P[27];
    const float* blin = P[28];

    // workspace layout
    float* bufA = (float*)d_ws;              // N x 128 (agg)
    float* bufB = bufA + (size_t)NN * 128;   // N x 128 (layer out)
    float* logits = bufB + (size_t)NN * 128; // N
    unsigned* gmax = (unsigned*)(logits + NN);   // G
    float* gsum = (float*)(gmax + NG);           // G
    int* deg    = (int*)(gsum + NG);             // N
    int* rowptr = deg + NN;                      // N+1
    int* cur    = rowptr + NN + 1;               // N
    int* esrc   = cur + NN;                      // E
    float* outp = (float*)d_out;

    const int TB = 256;

    // ---- build CSR (once per call) ----
    hipMemsetAsync(deg, 0, NN * sizeof(int), stream);
    hist_deg<<<(NE + TB - 1) / TB, TB, 0, stream>>>(dstI, deg);
    scan_deg<<<1, 256, 0, stream>>>(deg, rowptr, cur);
    fill_csr<<<(NE + TB - 1) / TB, TB, 0, stream>>>(srcI, dstI, cur, esrc);

    const int GATHER_BLOCKS = (NN + 3) / 4;

    // ---- layer 0: din=128, dout=128, relu ----
    gather_agg<128><<<GATHER_BLOCKS, 256, 0, stream>>>(x, esrc, rowptr, bufA);
    mlp_bn<128, 128><<<(NN + 1) / 2, dim3(128, 2), 0, stream>>>(
        bufA, bufB, P[3], P[4], P[5], P[6], P[7], P[8], P[9], P[10], 1);

    // ---- layer 1: din=128, dout=64, relu ----
    gather_agg<128><<<GATHER_BLOCKS, 256, 0, stream>>>(bufB, esrc, rowptr, bufA);
    mlp_bn<128, 64><<<(NN + 3) / 4, dim3(64, 4), 0, stream>>>(
        bufA, bufB, P[11], P[12], P[13], P[14], P[15], P[16], P[17], P[18], 1);

    // ---- layer 2: din=64, dout=32, no relu ----
    gather_agg<64><<<GATHER_BLOCKS, 256, 0, stream>>>(bufB, esrc, rowptr, bufA);
    mlp_bn<64, 32><<<(NN + 7) / 8, dim3(32, 8), 0, stream>>>(
        bufA, bufB, P[19], P[20], P[21], P[22], P[23], P[24], P[25], P[26], 0);

    // ---- head: logits + segment softmax ----
    logits_kernel<<<(NN + TB - 1) / TB, TB, 0, stream>>>(bufB, Wlin, blin, logits);
    init_gm<<<1, NG, 0, stream>>>(gmax, gsum);
    seg_max<<<(NN + TB - 1) / TB, TB, 0, stream>>>(logits, batch, gmax);
    seg_expsum<<<(NN + TB - 1) / TB, TB, 0, stream>>>(logits, batch, gmax, outp, gsum);
    seg_div<<<(NN + TB - 1) / TB, TB, 0, stream>>>(outp, batch, gsum);
}

// Round 3
// 720.964 us; speedup vs baseline: 5.4835x; 1.3794x over previous
//
#include <hip/hip_runtime.h>

#define NN 50000
#define NE 800000
#define NG 256

// ---------- helpers ----------
__device__ __forceinline__ unsigned fkey(float f) {
    unsigned u = __float_as_uint(f);
    return (u & 0x80000000u) ? ~u : (u | 0x80000000u);
}
__device__ __forceinline__ float funkey(unsigned k) {
    unsigned u = (k & 0x80000000u) ? (k ^ 0x80000000u) : ~k;
    return __uint_as_float(u);
}

// ---------- CSR build ----------
__global__ void hist_deg(const int* __restrict__ dst, int* __restrict__ deg) {
    int e = blockIdx.x * blockDim.x + threadIdx.x;
    if (e < NE) atomicAdd(&deg[dst[e]], 1);
}

__global__ void scan_deg(const int* __restrict__ deg, int* __restrict__ rowptr,
                         int* __restrict__ cur) {
    __shared__ int part[256];
    __shared__ int tmp[256];
    const int CH = (NN + 255) / 256;
    int t = threadIdx.x;
    int lo = t * CH, hi = min(lo + CH, NN);
    int s = 0;
    for (int i = lo; i < hi; i++) s += deg[i];
    part[t] = s;
    __syncthreads();
    for (int off = 1; off < 256; off <<= 1) {
        int v = part[t];
        int add = (t >= off) ? part[t - off] : 0;
        __syncthreads();
        tmp[t] = v + add;
        __syncthreads();
        part[t] = tmp[t];
        __syncthreads();
    }
    int run = (t == 0) ? 0 : part[t - 1];
    for (int i = lo; i < hi; i++) {
        rowptr[i] = run;
        cur[i] = run;
        run += deg[i];
    }
    if (t == 255) rowptr[NN] = NE;
}

__global__ void fill_csr(const int* __restrict__ src, const int* __restrict__ dst,
                         int* __restrict__ cur, int* __restrict__ esrc) {
    int e = blockIdx.x * blockDim.x + threadIdx.x;
    if (e >= NE) return;
    int p = atomicAdd(&cur[dst[e]], 1);
    esrc[p] = src[e];
}

// ---------- gather: agg[n] = x[n] + sum_{e in CSR[n]} x[esrc[e]] ----------
// wave per node; indices loaded cooperatively, broadcast by shfl; 4-deep MLP
template <int DIN>
__global__ void gather_agg(const float* __restrict__ x, const int* __restrict__ esrc,
                           const int* __restrict__ rowptr, float* __restrict__ agg) {
    int wave = threadIdx.x >> 6, lane = threadIdx.x & 63;
    int node = blockIdx.x * 4 + wave;
    if (node >= NN) return;
    int beg = rowptr[node], end = rowptr[node + 1];
    if (DIN == 128) {
        const float2* x2 = (const float2*)x;
        float2 acc = x2[(size_t)node * 64 + lane];
        for (int c = beg; c < end; c += 64) {
            int cnt = min(64, end - c);
            int myi = (lane < cnt) ? esrc[c + lane] : 0;
            int i = 0;
            for (; i + 4 <= cnt; i += 4) {
                int s0 = __shfl(myi, i), s1 = __shfl(myi, i + 1);
                int s2 = __shfl(myi, i + 2), s3 = __shfl(myi, i + 3);
                float2 v0 = x2[(size_t)s0 * 64 + lane];
                float2 v1 = x2[(size_t)s1 * 64 + lane];
                float2 v2 = x2[(size_t)s2 * 64 + lane];
                float2 v3 = x2[(size_t)s3 * 64 + lane];
                acc.x += (v0.x + v1.x) + (v2.x + v3.x);
                acc.y += (v0.y + v1.y) + (v2.y + v3.y);
            }
            for (; i < cnt; i++) {
                int s = __shfl(myi, i);
                float2 v = x2[(size_t)s * 64 + lane];
                acc.x += v.x; acc.y += v.y;
            }
        }
        ((float2*)agg)[(size_t)node * 64 + lane] = acc;
    } else {  // DIN == 64
        float acc = x[(size_t)node * 64 + lane];
        for (int c = beg; c < end; c += 64) {
            int cnt = min(64, end - c);
            int myi = (lane < cnt) ? esrc[c + lane] : 0;
            int i = 0;
            for (; i + 4 <= cnt; i += 4) {
                int s0 = __shfl(myi, i), s1 = __shfl(myi, i + 1);
                int s2 = __shfl(myi, i + 2), s3 = __shfl(myi, i + 3);
                float v0 = x[(size_t)s0 * 64 + lane];
                float v1 = x[(size_t)s1 * 64 + lane];
                float v2 = x[(size_t)s2 * 64 + lane];
                float v3 = x[(size_t)s3 * 64 + lane];
                acc += (v0 + v1) + (v2 + v3);
            }
            for (; i < cnt; i++)
                acc += x[(size_t)__shfl(myi, i) * 64 + lane];
        }
        agg[(size_t)node * 64 + lane] = acc;
    }
}

// ---------- tiled MLP + BN ----------
// 64-node tile in LDS (padded +4 -> <=2-way bank aliasing = free), register tile
// RPT x 4 per thread, W via float4 broadcast loads (L1-resident), mid reuses LDS.
template <int DIN, int DOUT, int RELU>
__global__ __launch_bounds__(256) void mlp_bn_tiled(
        const float* __restrict__ agg, float* __restrict__ out,
        const float* __restrict__ W1, const float* __restrict__ b1,
        const float* __restrict__ W2, const float* __restrict__ b2,
        const float* __restrict__ gamma, const float* __restrict__ beta,
        const float* __restrict__ mean, const float* __restrict__ var) {
    constexpr int MT  = 64;
    constexpr int CT  = DOUT / 4;   // col-threads
    constexpr int RT  = 256 / CT;   // row-threads
    constexpr int RPT = MT / RT;    // rows per thread
    constexpr int LDI = DIN + 4;
    constexpr int LDM = DOUT + 4;
    __shared__ float sh[MT * LDI];

    const int tid = threadIdx.x;
    const int colid = tid % CT, rowid = tid / CT;
    const int c0 = colid * 4, r0 = rowid * RPT;
    const int nodeBase = blockIdx.x * MT;

    // stage agg tile (coalesced float4)
    constexpr int NV = MT * (DIN / 4);
    for (int idx = tid; idx < NV; idx += 256) {
        int row = idx / (DIN / 4), c4 = idx % (DIN / 4);
        int node = nodeBase + row;
        float4 v = (node < NN) ? ((const float4*)agg)[(size_t)node * (DIN / 4) + c4]
                               : make_float4(0.f, 0.f, 0.f, 0.f);
        *(float4*)&sh[row * LDI + c4 * 4] = v;
    }
    __syncthreads();

    float acc[RPT][4];

    // ---- GEMM1: h = relu(tile @ W1 + b1) ----
    {
        float4 bv = *(const float4*)&b1[c0];
        #pragma unroll
        for (int i = 0; i < RPT; i++) {
            acc[i][0] = bv.x; acc[i][1] = bv.y; acc[i][2] = bv.z; acc[i][3] = bv.w;
        }
        #pragma unroll 2
        for (int k4 = 0; k4 < DIN / 4; k4++) {
            float4 w[4];
            #pragma unroll
            for (int kk = 0; kk < 4; kk++)
                w[kk] = *(const float4*)&W1[(k4 * 4 + kk) * DOUT + c0];
            #pragma unroll
            for (int i = 0; i < RPT; i++) {
                float4 a = *(const float4*)&sh[(r0 + i) * LDI + k4 * 4];
                const float av[4] = {a.x, a.y, a.z, a.w};
                #pragma unroll
                for (int kk = 0; kk < 4; kk++) {
                    const float* wp = (const float*)&w[kk];
                    #pragma unroll
                    for (int j = 0; j < 4; j++)
                        acc[i][j] = fmaf(av[kk], wp[j], acc[i][j]);
                }
            }
        }
    }
    __syncthreads();  // all GEMM1 reads of sh done
    #pragma unroll
    for (int i = 0; i < RPT; i++) {
        float4 h;
        h.x = fmaxf(acc[i][0], 0.f); h.y = fmaxf(acc[i][1], 0.f);
        h.z = fmaxf(acc[i][2], 0.f); h.w = fmaxf(acc[i][3], 0.f);
        *(float4*)&sh[(r0 + i) * LDM + c0] = h;
    }
    __syncthreads();

    // ---- GEMM2: z = h @ W2 + b2 ----
    {
        float4 bv = *(const float4*)&b2[c0];
        #pragma unroll
        for (int i = 0; i < RPT; i++) {
            acc[i][0] = bv.x; acc[i][1] = bv.y; acc[i][2] = bv.z; acc[i][3] = bv.w;
        }
        #pragma unroll 2
        for (int k4 = 0; k4 < DOUT / 4; k4++) {
            float4 w[4];
            #pragma unroll
            for (int kk = 0; kk < 4; kk++)
                w[kk] = *(const float4*)&W2[(k4 * 4 + kk) * DOUT + c0];
            #pragma unroll
            for (int i = 0; i < RPT; i++) {
                float4 a = *(const float4*)&sh[(r0 + i) * LDM + k4 * 4];
                const float av[4] = {a.x, a.y, a.z, a.w};
                #pragma unroll
                for (int kk = 0; kk < 4; kk++) {
                    const float* wp = (const float*)&w[kk];
                    #pragma unroll
                    for (int j = 0; j < 4; j++)
                        acc[i][j] = fmaf(av[kk], wp[j], acc[i][j]);
                }
            }
        }
    }

    // ---- BN (+ReLU) + store ----
    float4 gv = *(const float4*)&gamma[c0];
    float4 bev = *(const float4*)&beta[c0];
    float4 mv = *(const float4*)&mean[c0];
    float4 vv = *(const float4*)&var[c0];
    float scale[4], shift[4];
    const float* gp = (const float*)&gv; const float* bp = (const float*)&bev;
    const float* mp = (const float*)&mv; const float* vp = (const float*)&vv;
    #pragma unroll
    for (int j = 0; j < 4; j++) {
        scale[j] = gp[j] * (1.0f / sqrtf(vp[j] + 1e-5f));
        shift[j] = bp[j] - mp[j] * scale[j];
    }
    #pragma unroll
    for (int i = 0; i < RPT; i++) {
        int node = nodeBase + r0 + i;
        if (node < NN) {
            float4 o;
            float* op = (float*)&o;
            #pragma unroll
            for (int j = 0; j < 4; j++) {
                float z = fmaf(acc[i][j], scale[j], shift[j]);
                op[j] = RELU ? fmaxf(z, 0.f) : z;
            }
            *(float4*)&out[(size_t)node * DOUT + c0] = o;
        }
    }
}

// ---------- head ----------
__global__ void logits_kernel(const float* __restrict__ x, const float* __restrict__ Wl,
                              const float* __restrict__ bl, float* __restrict__ logits) {
    int n = blockIdx.x * blockDim.x + threadIdx.x;
    if (n >= NN) return;
    float acc = bl[0];
    #pragma unroll
    for (int k = 0; k < 32; k++)
        acc = fmaf(x[(size_t)n * 32 + k], Wl[k], acc);
    logits[n] = acc * 0.2f;  // / TEMP (5.0)
}

__global__ void init_gm(unsigned* __restrict__ gmax, float* __restrict__ gsum) {
    int g = threadIdx.x;
    if (g < NG) { gmax[g] = 0u; gsum[g] = 0.f; }
}

__global__ void seg_max(const float* __restrict__ logits, const int* __restrict__ batch,
                        unsigned* __restrict__ gmax) {
    int n = blockIdx.x * blockDim.x + threadIdx.x;
    if (n >= NN) return;
    atomicMax(&gmax[batch[n]], fkey(logits[n]));
}

__global__ void seg_expsum(const float* __restrict__ logits, const int* __restrict__ batch,
                           const unsigned* __restrict__ gmax, float* __restrict__ e_out,
                           float* __restrict__ gsum) {
    int n = blockIdx.x * blockDim.x + threadIdx.x;
    if (n >= NN) return;
    int g = batch[n];
    float e = expf(logits[n] - funkey(gmax[g]));
    e_out[n] = e;
    atomicAdd(&gsum[g], e);
}

__global__ void seg_div(float* __restrict__ out, const int* __restrict__ batch,
                        const float* __restrict__ gsum) {
    int n = blockIdx.x * blockDim.x + threadIdx.x;
    if (n >= NN) return;
    out[n] = out[n] / gsum[batch[n]];
}

// ---------- launch ----------
extern "C" void kernel_launch(void* const* d_in, const int* in_sizes, int n_in,
                              void* d_out, int out_size, void* d_ws, size_t ws_size,
                              hipStream_t stream) {
    const float* x    = (const float*)d_in[0];
    const int*   ei   = (const int*)d_in[1];
    const int*   srcI = ei;
    const int*   dstI = ei + NE;
    const int*   batch = (const int*)d_in[2];

    const float* P[29];
    for (int i = 0; i < 29; i++) P[i] = (const float*)d_in[i];
    const float* Wlin = P[27];
    const float* blin = P[28];

    float* bufA = (float*)d_ws;              // N x 128 (agg)
    float* bufB = bufA + (size_t)NN * 128;   // N x 128 (layer out)
    float* logits = bufB + (size_t)NN * 128; // N
    unsigned* gmax = (unsigned*)(logits + NN);
    float* gsum = (float*)(gmax + NG);
    int* deg    = (int*)(gsum + NG);
    int* rowptr = deg + NN;
    int* cur    = rowptr + NN + 1;
    int* esrc   = cur + NN;
    float* outp = (float*)d_out;

    const int TB = 256;

    // ---- build CSR ----
    hipMemsetAsync(deg, 0, NN * sizeof(int), stream);
    hist_deg<<<(NE + TB - 1) / TB, TB, 0, stream>>>(dstI, deg);
    scan_deg<<<1, 256, 0, stream>>>(deg, rowptr, cur);
    fill_csr<<<(NE + TB - 1) / TB, TB, 0, stream>>>(srcI, dstI, cur, esrc);

    const int GATHER_BLOCKS = (NN + 3) / 4;
    const int MLP_BLOCKS = (NN + 63) / 64;

    // ---- layer 0 ----
    gather_agg<128><<<GATHER_BLOCKS, 256, 0, stream>>>(x, esrc, rowptr, bufA);
    mlp_bn_tiled<128, 128, 1><<<MLP_BLOCKS, 256, 0, stream>>>(
        bufA, bufB, P[3], P[4], P[5], P[6], P[7], P[8], P[9], P[10]);

    // ---- layer 1 ----
    gather_agg<128><<<GATHER_BLOCKS, 256, 0, stream>>>(bufB, esrc, rowptr, bufA);
    mlp_bn_tiled<128, 64, 1><<<MLP_BLOCKS, 256, 0, stream>>>(
        bufA, bufB, P[11], P[12], P[13], P[14], P[15], P[16], P[17], P[18]);

    // ---- layer 2 ----
    gather_agg<64><<<GATHER_BLOCKS, 256, 0, stream>>>(bufB, esrc, rowptr, bufA);
    mlp_bn_tiled<64, 32, 0><<<MLP_BLOCKS, 256, 0, stream>>>(
        bufA, bufB, P[19], P[20], P[21], P[22], P[23], P[24], P[25], P[26]);

    // ---- head ----
    logits_kernel<<<(NN + TB - 1) / TB, TB, 0, stream>>>(bufB, Wlin, blin, logits);
    init_gm<<<1, NG, 0, stream>>>(gmax, gsum);
    seg_max<<<(NN + TB - 1) / TB, TB, 0, stream>>>(logits, batch, gmax);
    seg_expsum<<<(NN + TB - 1) / TB, TB, 0, stream>>>(logits, batch, gmax, outp, gsum);
    seg_div<<<(NN + TB - 1) / TB, TB, 0, stream>>>(outp, batch, gsum);
}

// Round 4
// 614.624 us; speedup vs baseline: 6.4323x; 1.1730x over previous
//
#include <hip/hip_runtime.h>

#define NN 50000
#define NE 800000
#define NG 256
#define NB ((NN + 255) / 256)   // 196 scan blocks

// ---------- helpers ----------
__device__ __forceinline__ unsigned fkey(float f) {
    unsigned u = __float_as_uint(f);
    return (u & 0x80000000u) ? ~u : (u | 0x80000000u);
}
__device__ __forceinline__ float funkey(unsigned k) {
    unsigned u = (k & 0x80000000u) ? (k ^ 0x80000000u) : ~k;
    return __uint_as_float(u);
}

// ---------- CSR build ----------
__global__ void hist_deg(const int* __restrict__ dst, int* __restrict__ deg) {
    int e = blockIdx.x * blockDim.x + threadIdx.x;
    if (e < NE) atomicAdd(&deg[dst[e]], 1);
}

// per-block inclusive scan of deg -> iscan, block totals -> bsum
__global__ void block_scan(const int* __restrict__ deg, int* __restrict__ iscan,
                           int* __restrict__ bsum) {
    __shared__ int sh[256];
    int t = threadIdx.x;
    int i = blockIdx.x * 256 + t;
    int v = (i < NN) ? deg[i] : 0;
    sh[t] = v;
    __syncthreads();
    #pragma unroll
    for (int off = 1; off < 256; off <<= 1) {
        int add = (t >= off) ? sh[t - off] : 0;
        __syncthreads();
        sh[t] += add;
        __syncthreads();
    }
    if (i < NN) iscan[i] = sh[t];
    if (t == 255) bsum[blockIdx.x] = sh[255];
}

// single tiny block: exclusive offsets of the 196 block sums
__global__ void scan_bsum(const int* __restrict__ bsum, int* __restrict__ boff) {
    __shared__ int sh[256];
    int t = threadIdx.x;
    int v = (t < NB) ? bsum[t] : 0;
    sh[t] = v;
    __syncthreads();
    #pragma unroll
    for (int off = 1; off < 256; off <<= 1) {
        int add = (t >= off) ? sh[t - off] : 0;
        __syncthreads();
        sh[t] += add;
        __syncthreads();
    }
    if (t < NB) boff[t] = sh[t] - v;  // exclusive
}

__global__ void finalize_rowptr(const int* __restrict__ deg, const int* __restrict__ iscan,
                                const int* __restrict__ boff, int* __restrict__ rowptr,
                                int* __restrict__ cur) {
    int i = blockIdx.x * 256 + threadIdx.x;
    if (i < NN) {
        int r = iscan[i] - deg[i] + boff[blockIdx.x];
        rowptr[i] = r;
        cur[i] = r;
    }
    if (i == 0) rowptr[NN] = NE;
}

__global__ void fill_csr(const int* __restrict__ src, const int* __restrict__ dst,
                         int* __restrict__ cur, int* __restrict__ esrc) {
    int e = blockIdx.x * blockDim.x + threadIdx.x;
    if (e >= NE) return;
    int p = atomicAdd(&cur[dst[e]], 1);
    esrc[p] = src[e];
}

// ---------- gather: agg[n] = x[n] + sum_{e in CSR[n]} x[esrc[e]] ----------
template <int DIN>
__global__ void gather_agg(const float* __restrict__ x, const int* __restrict__ esrc,
                           const int* __restrict__ rowptr, float* __restrict__ agg) {
    int wave = threadIdx.x >> 6, lane = threadIdx.x & 63;
    int node = blockIdx.x * 4 + wave;
    if (node >= NN) return;
    int beg = rowptr[node], end = rowptr[node + 1];
    if (DIN == 128) {
        const float2* x2 = (const float2*)x;
        float2 acc = x2[(size_t)node * 64 + lane];
        for (int c = beg; c < end; c += 64) {
            int cnt = min(64, end - c);
            int myi = (lane < cnt) ? esrc[c + lane] : 0;
            int i = 0;
            for (; i + 4 <= cnt; i += 4) {
                int s0 = __shfl(myi, i), s1 = __shfl(myi, i + 1);
                int s2 = __shfl(myi, i + 2), s3 = __shfl(myi, i + 3);
                float2 v0 = x2[(size_t)s0 * 64 + lane];
                float2 v1 = x2[(size_t)s1 * 64 + lane];
                float2 v2 = x2[(size_t)s2 * 64 + lane];
                float2 v3 = x2[(size_t)s3 * 64 + lane];
                acc.x += (v0.x + v1.x) + (v2.x + v3.x);
                acc.y += (v0.y + v1.y) + (v2.y + v3.y);
            }
            for (; i < cnt; i++) {
                int s = __shfl(myi, i);
                float2 v = x2[(size_t)s * 64 + lane];
                acc.x += v.x; acc.y += v.y;
            }
        }
        ((float2*)agg)[(size_t)node * 64 + lane] = acc;
    } else {  // DIN == 64
        float acc = x[(size_t)node * 64 + lane];
        for (int c = beg; c < end; c += 64) {
            int cnt = min(64, end - c);
            int myi = (lane < cnt) ? esrc[c + lane] : 0;
            int i = 0;
            for (; i + 4 <= cnt; i += 4) {
                int s0 = __shfl(myi, i), s1 = __shfl(myi, i + 1);
                int s2 = __shfl(myi, i + 2), s3 = __shfl(myi, i + 3);
                float v0 = x[(size_t)s0 * 64 + lane];
                float v1 = x[(size_t)s1 * 64 + lane];
                float v2 = x[(size_t)s2 * 64 + lane];
                float v3 = x[(size_t)s3 * 64 + lane];
                acc += (v0 + v1) + (v2 + v3);
            }
            for (; i < cnt; i++)
                acc += x[(size_t)__shfl(myi, i) * 64 + lane];
        }
        agg[(size_t)node * 64 + lane] = acc;
    }
}

// ---------- tiled MLP + BN ----------
template <int DIN, int DOUT, int RELU>
__global__ __launch_bounds__(256) void mlp_bn_tiled(
        const float* __restrict__ agg, float* __restrict__ out,
        const float* __restrict__ W1, const float* __restrict__ b1,
        const float* __restrict__ W2, const float* __restrict__ b2,
        const float* __restrict__ gamma, const float* __restrict__ beta,
        const float* __restrict__ mean, const float* __restrict__ var) {
    constexpr int MT  = 64;
    constexpr int CT  = DOUT / 4;
    constexpr int RT  = 256 / CT;
    constexpr int RPT = MT / RT;
    constexpr int LDI = DIN + 4;
    constexpr int LDM = DOUT + 4;
    __shared__ float sh[MT * LDI];

    const int tid = threadIdx.x;
    const int colid = tid % CT, rowid = tid / CT;
    const int c0 = colid * 4, r0 = rowid * RPT;
    const int nodeBase = blockIdx.x * MT;

    constexpr int NV = MT * (DIN / 4);
    for (int idx = tid; idx < NV; idx += 256) {
        int row = idx / (DIN / 4), c4 = idx % (DIN / 4);
        int node = nodeBase + row;
        float4 v = (node < NN) ? ((const float4*)agg)[(size_t)node * (DIN / 4) + c4]
                               : make_float4(0.f, 0.f, 0.f, 0.f);
        *(float4*)&sh[row * LDI + c4 * 4] = v;
    }
    __syncthreads();

    float acc[RPT][4];

    // ---- GEMM1 ----
    {
        float4 bv = *(const float4*)&b1[c0];
        #pragma unroll
        for (int i = 0; i < RPT; i++) {
            acc[i][0] = bv.x; acc[i][1] = bv.y; acc[i][2] = bv.z; acc[i][3] = bv.w;
        }
        #pragma unroll 2
        for (int k4 = 0; k4 < DIN / 4; k4++) {
            float4 w[4];
            #pragma unroll
            for (int kk = 0; kk < 4; kk++)
                w[kk] = *(const float4*)&W1[(k4 * 4 + kk) * DOUT + c0];
            #pragma unroll
            for (int i = 0; i < RPT; i++) {
                float4 a = *(const float4*)&sh[(r0 + i) * LDI + k4 * 4];
                const float av[4] = {a.x, a.y, a.z, a.w};
                #pragma unroll
                for (int kk = 0; kk < 4; kk++) {
                    const float* wp = (const float*)&w[kk];
                    #pragma unroll
                    for (int j = 0; j < 4; j++)
                        acc[i][j] = fmaf(av[kk], wp[j], acc[i][j]);
                }
            }
        }
    }
    __syncthreads();
    #pragma unroll
    for (int i = 0; i < RPT; i++) {
        float4 h;
        h.x = fmaxf(acc[i][0], 0.f); h.y = fmaxf(acc[i][1], 0.f);
        h.z = fmaxf(acc[i][2], 0.f); h.w = fmaxf(acc[i][3], 0.f);
        *(float4*)&sh[(r0 + i) * LDM + c0] = h;
    }
    __syncthreads();

    // ---- GEMM2 ----
    {
        float4 bv = *(const float4*)&b2[c0];
        #pragma unroll
        for (int i = 0; i < RPT; i++) {
            acc[i][0] = bv.x; acc[i][1] = bv.y; acc[i][2] = bv.z; acc[i][3] = bv.w;
        }
        #pragma unroll 2
        for (int k4 = 0; k4 < DOUT / 4; k4++) {
            float4 w[4];
            #pragma unroll
            for (int kk = 0; kk < 4; kk++)
                w[kk] = *(const float4*)&W2[(k4 * 4 + kk) * DOUT + c0];
            #pragma unroll
            for (int i = 0; i < RPT; i++) {
                float4 a = *(const float4*)&sh[(r0 + i) * LDM + k4 * 4];
                const float av[4] = {a.x, a.y, a.z, a.w};
                #pragma unroll
                for (int kk = 0; kk < 4; kk++) {
                    const float* wp = (const float*)&w[kk];
                    #pragma unroll
                    for (int j = 0; j < 4; j++)
                        acc[i][j] = fmaf(av[kk], wp[j], acc[i][j]);
                }
            }
        }
    }

    // ---- BN (+ReLU) + store ----
    float4 gv = *(const float4*)&gamma[c0];
    float4 bev = *(const float4*)&beta[c0];
    float4 mv = *(const float4*)&mean[c0];
    float4 vv = *(const float4*)&var[c0];
    float scale[4], shift[4];
    const float* gp = (const float*)&gv; const float* bp = (const float*)&bev;
    const float* mp = (const float*)&mv; const float* vp = (const float*)&vv;
    #pragma unroll
    for (int j = 0; j < 4; j++) {
        scale[j] = gp[j] * (1.0f / sqrtf(vp[j] + 1e-5f));
        shift[j] = bp[j] - mp[j] * scale[j];
    }
    #pragma unroll
    for (int i = 0; i < RPT; i++) {
        int node = nodeBase + r0 + i;
        if (node < NN) {
            float4 o;
            float* op = (float*)&o;
            #pragma unroll
            for (int j = 0; j < 4; j++) {
                float z = fmaf(acc[i][j], scale[j], shift[j]);
                op[j] = RELU ? fmaxf(z, 0.f) : z;
            }
            *(float4*)&out[(size_t)node * DOUT + c0] = o;
        }
    }
}

// ---------- head ----------
__global__ void logits_kernel(const float* __restrict__ x, const float* __restrict__ Wl,
                              const float* __restrict__ bl, float* __restrict__ logits) {
    int n = blockIdx.x * blockDim.x + threadIdx.x;
    if (n >= NN) return;
    float acc = bl[0];
    #pragma unroll
    for (int k = 0; k < 32; k++)
        acc = fmaf(x[(size_t)n * 32 + k], Wl[k], acc);
    logits[n] = acc * 0.2f;  // / TEMP (5.0)
}

__global__ void init_gm(unsigned* __restrict__ gmax, float* __restrict__ gsum) {
    int g = threadIdx.x;
    if (g < NG) { gmax[g] = 0u; gsum[g] = 0.f; }
}

__global__ void seg_max(const float* __restrict__ logits, const int* __restrict__ batch,
                        unsigned* __restrict__ gmax) {
    int n = blockIdx.x * blockDim.x + threadIdx.x;
    if (n >= NN) return;
    atomicMax(&gmax[batch[n]], fkey(logits[n]));
}

__global__ void seg_expsum(const float* __restrict__ logits, const int* __restrict__ batch,
                           const unsigned* __restrict__ gmax, float* __restrict__ e_out,
                           float* __restrict__ gsum) {
    int n = blockIdx.x * blockDim.x + threadIdx.x;
    if (n >= NN) return;
    int g = batch[n];
    float e = expf(logits[n] - funkey(gmax[g]));
    e_out[n] = e;
    atomicAdd(&gsum[g], e);
}

__global__ void seg_div(float* __restrict__ out, const int* __restrict__ batch,
                        const float* __restrict__ gsum) {
    int n = blockIdx.x * blockDim.x + threadIdx.x;
    if (n >= NN) return;
    out[n] = out[n] / gsum[batch[n]];
}

// ---------- launch ----------
extern "C" void kernel_launch(void* const* d_in, const int* in_sizes, int n_in,
                              void* d_out, int out_size, void* d_ws, size_t ws_size,
                              hipStream_t stream) {
    const float* x    = (const float*)d_in[0];
    const int*   ei   = (const int*)d_in[1];
    const int*   srcI = ei;
    const int*   dstI = ei + NE;
    const int*   batch = (const int*)d_in[2];

    const float* P[29];
    for (int i = 0; i < 29; i++) P[i] = (const float*)d_in[i];
    const float* Wlin = P[27];
    const float* blin = P[28];

    float* bufA = (float*)d_ws;              // N x 128 (agg)
    float* bufB = bufA + (size_t)NN * 128;   // N x 128 (layer out)
    float* logits = bufB + (size_t)NN * 128; // N
    unsigned* gmax = (unsigned*)(logits + NN);
    float* gsum = (float*)(gmax + NG);
    int* deg    = (int*)(gsum + NG);             // N
    int* iscan  = deg + NN;                      // N
    int* rowptr = iscan + NN;                    // N+1
    int* cur    = rowptr + NN + 1;               // N
    int* bsum   = cur + NN;                      // NB
    int* boff   = bsum + NB;                     // NB
    int* esrc   = boff + NB;                     // E
    float* outp = (float*)d_out;

    const int TB = 256;

    // ---- build CSR (parallel scan) ----
    hipMemsetAsync(deg, 0, NN * sizeof(int), stream);
    hist_deg<<<(NE + TB - 1) / TB, TB, 0, stream>>>(dstI, deg);
    block_scan<<<NB, 256, 0, stream>>>(deg, iscan, bsum);
    scan_bsum<<<1, 256, 0, stream>>>(bsum, boff);
    finalize_rowptr<<<NB, 256, 0, stream>>>(deg, iscan, boff, rowptr, cur);
    fill_csr<<<(NE + TB - 1) / TB, TB, 0, stream>>>(srcI, dstI, cur, esrc);

    const int GATHER_BLOCKS = (NN + 3) / 4;
    const int MLP_BLOCKS = (NN + 63) / 64;

    // ---- layer 0 ----
    gather_agg<128><<<GATHER_BLOCKS, 256, 0, stream>>>(x, esrc, rowptr, bufA);
    mlp_bn_tiled<128, 128, 1><<<MLP_BLOCKS, 256, 0, stream>>>(
        bufA, bufB, P[3], P[4], P[5], P[6], P[7], P[8], P[9], P[10]);

    // ---- layer 1 ----
    gather_agg<128><<<GATHER_BLOCKS, 256, 0, stream>>>(bufB, esrc, rowptr, bufA);
    mlp_bn_tiled<128, 64, 1><<<MLP_BLOCKS, 256, 0, stream>>>(
        bufA, bufB, P[11], P[12], P[13], P[14], P[15], P[16], P[17], P[18]);

    // ---- layer 2 ----
    gather_agg<64><<<GATHER_BLOCKS, 256, 0, stream>>>(bufB, esrc, rowptr, bufA);
    mlp_bn_tiled<64, 32, 0><<<MLP_BLOCKS, 256, 0, stream>>>(
        bufA, bufB, P[19], P[20], P[21], P[22], P[23], P[24], P[25], P[26]);

    // ---- head ----
    logits_kernel<<<(NN + TB - 1) / TB, TB, 0, stream>>>(bufB, Wlin, blin, logits);
    init_gm<<<1, NG, 0, stream>>>(gmax, gsum);
    seg_max<<<(NN + TB - 1) / TB, TB, 0, stream>>>(logits, batch, gmax);
    seg_expsum<<<(NN + TB - 1) / TB, TB, 0, stream>>>(logits, batch, gmax, outp, gsum);
    seg_div<<<(NN + TB - 1) / TB, TB, 0, stream>>>(outp, batch, gsum);
}

// Round 5
// 498.242 us; speedup vs baseline: 7.9347x; 1.2336x over previous
//
#include <hip/hip_runtime.h>

#define NN 50000
#define NE 800000
#define NG 256
#define NB ((NN + 255) / 256)   // scan blocks

// ---------- CSR build ----------
__global__ void hist_deg(const int* __restrict__ dst, int* __restrict__ deg) {
    int e = blockIdx.x * blockDim.x + threadIdx.x;
    if (e < NE) atomicAdd(&deg[dst[e]], 1);
}

__global__ void block_scan(const int* __restrict__ deg, int* __restrict__ iscan,
                           int* __restrict__ bsum) {
    __shared__ int sh[256];
    int t = threadIdx.x;
    int i = blockIdx.x * 256 + t;
    int v = (i < NN) ? deg[i] : 0;
    sh[t] = v;
    __syncthreads();
    #pragma unroll
    for (int off = 1; off < 256; off <<= 1) {
        int add = (t >= off) ? sh[t - off] : 0;
        __syncthreads();
        sh[t] += add;
        __syncthreads();
    }
    if (i < NN) iscan[i] = sh[t];
    if (t == 255) bsum[blockIdx.x] = sh[255];
}

__global__ void scan_bsum(const int* __restrict__ bsum, int* __restrict__ boff) {
    __shared__ int sh[256];
    int t = threadIdx.x;
    int v = (t < NB) ? bsum[t] : 0;
    sh[t] = v;
    __syncthreads();
    #pragma unroll
    for (int off = 1; off < 256; off <<= 1) {
        int add = (t >= off) ? sh[t - off] : 0;
        __syncthreads();
        sh[t] += add;
        __syncthreads();
    }
    if (t < NB) boff[t] = sh[t] - v;  // exclusive
}

__global__ void finalize_rowptr(const int* __restrict__ deg, const int* __restrict__ iscan,
                                const int* __restrict__ boff, int* __restrict__ rowptr,
                                int* __restrict__ cur) {
    int i = blockIdx.x * 256 + threadIdx.x;
    if (i < NN) {
        int r = iscan[i] - deg[i] + boff[blockIdx.x];
        rowptr[i] = r;
        cur[i] = r;
    }
    if (i == 0) rowptr[NN] = NE;
}

__global__ void fill_csr(const int* __restrict__ src, const int* __restrict__ dst,
                         int* __restrict__ cur, int* __restrict__ esrc) {
    int e = blockIdx.x * blockDim.x + threadIdx.x;
    if (e >= NE) return;
    int p = atomicAdd(&cur[dst[e]], 1);
    esrc[p] = src[e];
}

// ---------- gather: agg[n] = x[n] + sum_{e in CSR[n]} x[esrc[e]] ----------
template <int DIN>
__global__ void gather_agg(const float* __restrict__ x, const int* __restrict__ esrc,
                           const int* __restrict__ rowptr, float* __restrict__ agg) {
    int wave = threadIdx.x >> 6, lane = threadIdx.x & 63;
    int node = blockIdx.x * 4 + wave;
    if (node >= NN) return;
    int beg = rowptr[node], end = rowptr[node + 1];
    if (DIN == 128) {
        const float2* x2 = (const float2*)x;
        float2 acc = x2[(size_t)node * 64 + lane];
        for (int c = beg; c < end; c += 64) {
            int cnt = min(64, end - c);
            int myi = (lane < cnt) ? esrc[c + lane] : 0;
            int i = 0;
            for (; i + 4 <= cnt; i += 4) {
                int s0 = __shfl(myi, i), s1 = __shfl(myi, i + 1);
                int s2 = __shfl(myi, i + 2), s3 = __shfl(myi, i + 3);
                float2 v0 = x2[(size_t)s0 * 64 + lane];
                float2 v1 = x2[(size_t)s1 * 64 + lane];
                float2 v2 = x2[(size_t)s2 * 64 + lane];
                float2 v3 = x2[(size_t)s3 * 64 + lane];
                acc.x += (v0.x + v1.x) + (v2.x + v3.x);
                acc.y += (v0.y + v1.y) + (v2.y + v3.y);
            }
            for (; i < cnt; i++) {
                int s = __shfl(myi, i);
                float2 v = x2[(size_t)s * 64 + lane];
                acc.x += v.x; acc.y += v.y;
            }
        }
        ((float2*)agg)[(size_t)node * 64 + lane] = acc;
    } else {  // DIN == 64
        float acc = x[(size_t)node * 64 + lane];
        for (int c = beg; c < end; c += 64) {
            int cnt = min(64, end - c);
            int myi = (lane < cnt) ? esrc[c + lane] : 0;
            int i = 0;
            for (; i + 4 <= cnt; i += 4) {
                int s0 = __shfl(myi, i), s1 = __shfl(myi, i + 1);
                int s2 = __shfl(myi, i + 2), s3 = __shfl(myi, i + 3);
                float v0 = x[(size_t)s0 * 64 + lane];
                float v1 = x[(size_t)s1 * 64 + lane];
                float v2 = x[(size_t)s2 * 64 + lane];
                float v3 = x[(size_t)s3 * 64 + lane];
                acc += (v0 + v1) + (v2 + v3);
            }
            for (; i < cnt; i++)
                acc += x[(size_t)__shfl(myi, i) * 64 + lane];
        }
        agg[(size_t)node * 64 + lane] = acc;
    }
}

// ---------- tiled MLP + BN (MT=32: 16.9KB LDS -> ~6 blocks/CU) ----------
template <int DIN, int DOUT, int RELU>
__global__ __launch_bounds__(256) void mlp_bn_tiled(
        const float* __restrict__ agg, float* __restrict__ out,
        const float* __restrict__ W1, const float* __restrict__ b1,
        const float* __restrict__ W2, const float* __restrict__ b2,
        const float* __restrict__ gamma, const float* __restrict__ beta,
        const float* __restrict__ mean, const float* __restrict__ var) {
    constexpr int MT  = 32;
    constexpr int CT  = DOUT / 4;
    constexpr int RT  = 256 / CT;
    constexpr int RPT = MT / RT;
    constexpr int LDI = DIN + 4;
    constexpr int LDM = DOUT + 4;
    __shared__ float sh[MT * LDI];

    const int tid = threadIdx.x;
    const int colid = tid % CT, rowid = tid / CT;
    const int c0 = colid * 4, r0 = rowid * RPT;
    const int nodeBase = blockIdx.x * MT;

    constexpr int NV = MT * (DIN / 4);
    for (int idx = tid; idx < NV; idx += 256) {
        int row = idx / (DIN / 4), c4 = idx % (DIN / 4);
        int node = nodeBase + row;
        float4 v = (node < NN) ? ((const float4*)agg)[(size_t)node * (DIN / 4) + c4]
                               : make_float4(0.f, 0.f, 0.f, 0.f);
        *(float4*)&sh[row * LDI + c4 * 4] = v;
    }
    __syncthreads();

    float acc[RPT][4];

    // ---- GEMM1 ----
    {
        float4 bv = *(const float4*)&b1[c0];
        #pragma unroll
        for (int i = 0; i < RPT; i++) {
            acc[i][0] = bv.x; acc[i][1] = bv.y; acc[i][2] = bv.z; acc[i][3] = bv.w;
        }
        #pragma unroll 2
        for (int k4 = 0; k4 < DIN / 4; k4++) {
            float4 w[4];
            #pragma unroll
            for (int kk = 0; kk < 4; kk++)
                w[kk] = *(const float4*)&W1[(k4 * 4 + kk) * DOUT + c0];
            #pragma unroll
            for (int i = 0; i < RPT; i++) {
                float4 a = *(const float4*)&sh[(r0 + i) * LDI + k4 * 4];
                const float av[4] = {a.x, a.y, a.z, a.w};
                #pragma unroll
                for (int kk = 0; kk < 4; kk++) {
                    const float* wp = (const float*)&w[kk];
                    #pragma unroll
                    for (int j = 0; j < 4; j++)
                        acc[i][j] = fmaf(av[kk], wp[j], acc[i][j]);
                }
            }
        }
    }
    __syncthreads();
    #pragma unroll
    for (int i = 0; i < RPT; i++) {
        float4 h;
        h.x = fmaxf(acc[i][0], 0.f); h.y = fmaxf(acc[i][1], 0.f);
        h.z = fmaxf(acc[i][2], 0.f); h.w = fmaxf(acc[i][3], 0.f);
        *(float4*)&sh[(r0 + i) * LDM + c0] = h;
    }
    __syncthreads();

    // ---- GEMM2 ----
    {
        float4 bv = *(const float4*)&b2[c0];
        #pragma unroll
        for (int i = 0; i < RPT; i++) {
            acc[i][0] = bv.x; acc[i][1] = bv.y; acc[i][2] = bv.z; acc[i][3] = bv.w;
        }
        #pragma unroll 2
        for (int k4 = 0; k4 < DOUT / 4; k4++) {
            float4 w[4];
            #pragma unroll
            for (int kk = 0; kk < 4; kk++)
                w[kk] = *(const float4*)&W2[(k4 * 4 + kk) * DOUT + c0];
            #pragma unroll
            for (int i = 0; i < RPT; i++) {
                float4 a = *(const float4*)&sh[(r0 + i) * LDM + k4 * 4];
                const float av[4] = {a.x, a.y, a.z, a.w};
                #pragma unroll
                for (int kk = 0; kk < 4; kk++) {
                    const float* wp = (const float*)&w[kk];
                    #pragma unroll
                    for (int j = 0; j < 4; j++)
                        acc[i][j] = fmaf(av[kk], wp[j], acc[i][j]);
                }
            }
        }
    }

    // ---- BN (+ReLU) + store ----
    float4 gv = *(const float4*)&gamma[c0];
    float4 bev = *(const float4*)&beta[c0];
    float4 mv = *(const float4*)&mean[c0];
    float4 vv = *(const float4*)&var[c0];
    float scale[4], shift[4];
    const float* gp = (const float*)&gv; const float* bp = (const float*)&bev;
    const float* mp = (const float*)&mv; const float* vp = (const float*)&vv;
    #pragma unroll
    for (int j = 0; j < 4; j++) {
        scale[j] = gp[j] * (1.0f / sqrtf(vp[j] + 1e-5f));
        shift[j] = bp[j] - mp[j] * scale[j];
    }
    #pragma unroll
    for (int i = 0; i < RPT; i++) {
        int node = nodeBase + r0 + i;
        if (node < NN) {
            float4 o;
            float* op = (float*)&o;
            #pragma unroll
            for (int j = 0; j < 4; j++) {
                float z = fmaf(acc[i][j], scale[j], shift[j]);
                op[j] = RELU ? fmaxf(z, 0.f) : z;
            }
            *(float4*)&out[(size_t)node * DOUT + c0] = o;
        }
    }
}

// ---------- head: graph boundaries (batch is sorted) ----------
__global__ void find_bounds(const int* __restrict__ batch, int* __restrict__ gstart) {
    int n = blockIdx.x * 256 + threadIdx.x;
    if (n >= NN) return;
    int b = batch[n];
    if (n == 0) {
        for (int g = 0; g <= b; g++) gstart[g] = 0;
    } else {
        int p = batch[n - 1];
        for (int g = p + 1; g <= b; g++) gstart[g] = n;
    }
    if (n == NN - 1) {
        for (int g = b + 1; g <= NG; g++) gstart[g] = NN;
    }
}

// one block per graph: logits + max + exp-sum + normalize, no global atomics
__global__ __launch_bounds__(256) void seg_softmax(
        const float* __restrict__ x32, const float* __restrict__ Wl,
        const float* __restrict__ bl, const int* __restrict__ gstart,
        float* __restrict__ out) {
    __shared__ float sWl[32];
    __shared__ float slog[1024];
    __shared__ float sred[4];
    __shared__ float sbc[2];
    int g = blockIdx.x;
    int beg = gstart[g], end = gstart[g + 1];
    int cnt = end - beg;
    int t = threadIdx.x;
    if (cnt <= 0) return;
    if (t < 32) sWl[t] = Wl[t];
    __syncthreads();
    bool fits = (cnt <= 1024);
    float bias = bl[0];

    // pass 1: logits + local max
    float lmax = -3.402823466e+38f;
    for (int i = t; i < cnt; i += 256) {
        const float4* xr = (const float4*)(x32 + (size_t)(beg + i) * 32);
        float acc = bias;
        #pragma unroll
        for (int q = 0; q < 8; q++) {
            float4 v = xr[q];
            acc = fmaf(v.x, sWl[q * 4 + 0], acc);
            acc = fmaf(v.y, sWl[q * 4 + 1], acc);
            acc = fmaf(v.z, sWl[q * 4 + 2], acc);
            acc = fmaf(v.w, sWl[q * 4 + 3], acc);
        }
        float lg = acc * 0.2f;
        if (fits) slog[i] = lg;
        lmax = fmaxf(lmax, lg);
    }
    #pragma unroll
    for (int off = 32; off > 0; off >>= 1)
        lmax = fmaxf(lmax, __shfl_down(lmax, off));
    if ((t & 63) == 0) sred[t >> 6] = lmax;
    __syncthreads();
    if (t == 0) {
        float v = fmaxf(fmaxf(sred[0], sred[1]), fmaxf(sred[2], sred[3]));
        sbc[0] = v;
    }
    __syncthreads();
    float gm = sbc[0];

    // pass 2: exp + sum
    float lsum = 0.f;
    for (int i = t; i < cnt; i += 256) {
        float lg;
        if (fits) lg = slog[i];
        else {
            const float4* xr = (const float4*)(x32 + (size_t)(beg + i) * 32);
            float acc = bias;
            #pragma unroll
            for (int q = 0; q < 8; q++) {
                float4 v = xr[q];
                acc = fmaf(v.x, sWl[q * 4 + 0], acc);
                acc = fmaf(v.y, sWl[q * 4 + 1], acc);
                acc = fmaf(v.z, sWl[q * 4 + 2], acc);
                acc = fmaf(v.w, sWl[q * 4 + 3], acc);
            }
            lg = acc * 0.2f;
        }
        float e = expf(lg - gm);
        if (fits) slog[i] = e;
        lsum += e;
    }
    #pragma unroll
    for (int off = 32; off > 0; off >>= 1)
        lsum += __shfl_down(lsum, off);
    __syncthreads();  // sred reuse
    if ((t & 63) == 0) sred[t >> 6] = lsum;
    __syncthreads();
    if (t == 0) sbc[1] = (sred[0] + sred[1]) + (sred[2] + sred[3]);
    __syncthreads();
    float inv = 1.0f / sbc[1];

    // pass 3: normalize + store
    for (int i = t; i < cnt; i += 256) {
        float e;
        if (fits) e = slog[i];
        else {
            const float4* xr = (const float4*)(x32 + (size_t)(beg + i) * 32);
            float acc = bias;
            #pragma unroll
            for (int q = 0; q < 8; q++) {
                float4 v = xr[q];
                acc = fmaf(v.x, sWl[q * 4 + 0], acc);
                acc = fmaf(v.y, sWl[q * 4 + 1], acc);
                acc = fmaf(v.z, sWl[q * 4 + 2], acc);
                acc = fmaf(v.w, sWl[q * 4 + 3], acc);
            }
            e = expf(acc * 0.2f - gm);
        }
        out[beg + i] = e * inv;
    }
}

// ---------- launch ----------
extern "C" void kernel_launch(void* const* d_in, const int* in_sizes, int n_in,
                              void* d_out, int out_size, void* d_ws, size_t ws_size,
                              hipStream_t stream) {
    const float* x    = (const float*)d_in[0];
    const int*   ei   = (const int*)d_in[1];
    const int*   srcI = ei;
    const int*   dstI = ei + NE;
    const int*   batch = (const int*)d_in[2];

    const float* P[29];
    for (int i = 0; i < 29; i++) P[i] = (const float*)d_in[i];
    const float* Wlin = P[27];
    const float* blin = P[28];

    float* bufA = (float*)d_ws;              // N x 128 (agg)
    float* bufB = bufA + (size_t)NN * 128;   // N x 128 (layer out)
    int* gstart = (int*)(bufB + (size_t)NN * 128);  // NG+1
    int* deg    = gstart + NG + 1;               // N
    int* iscan  = deg + NN;                      // N
    int* rowptr = iscan + NN;                    // N+1
    int* cur    = rowptr + NN + 1;               // N
    int* bsum   = cur + NN;                      // NB
    int* boff   = bsum + NB;                     // NB
    int* esrc   = boff + NB;                     // E
    float* outp = (float*)d_out;

    const int TB = 256;

    // ---- build CSR ----
    hipMemsetAsync(deg, 0, NN * sizeof(int), stream);
    hist_deg<<<(NE + TB - 1) / TB, TB, 0, stream>>>(dstI, deg);
    block_scan<<<NB, 256, 0, stream>>>(deg, iscan, bsum);
    scan_bsum<<<1, 256, 0, stream>>>(bsum, boff);
    finalize_rowptr<<<NB, 256, 0, stream>>>(deg, iscan, boff, rowptr, cur);
    fill_csr<<<(NE + TB - 1) / TB, TB, 0, stream>>>(srcI, dstI, cur, esrc);

    // graph bounds (independent of CSR; overlap fine)
    find_bounds<<<NB, 256, 0, stream>>>(batch, gstart);

    const int GATHER_BLOCKS = (NN + 3) / 4;
    const int MLP_BLOCKS = (NN + 31) / 32;

    // ---- layer 0 ----
    gather_agg<128><<<GATHER_BLOCKS, 256, 0, stream>>>(x, esrc, rowptr, bufA);
    mlp_bn_tiled<128, 128, 1><<<MLP_BLOCKS, 256, 0, stream>>>(
        bufA, bufB, P[3], P[4], P[5], P[6], P[7], P[8], P[9], P[10]);

    // ---- layer 1 ----
    gather_agg<128><<<GATHER_BLOCKS, 256, 0, stream>>>(bufB, esrc, rowptr, bufA);
    mlp_bn_tiled<128, 64, 1><<<MLP_BLOCKS, 256, 0, stream>>>(
        bufA, bufB, P[11], P[12], P[13], P[14], P[15], P[16], P[17], P[18]);

    // ---- layer 2 ----
    gather_agg<64><<<GATHER_BLOCKS, 256, 0, stream>>>(bufB, esrc, rowptr, bufA);
    mlp_bn_tiled<64, 32, 0><<<MLP_BLOCKS, 256, 0, stream>>>(
        bufA, bufB, P[19], P[20], P[21], P[22], P[23], P[24], P[25], P[26]);

    // ---- head: fused per-graph softmax ----
    seg_softmax<<<NG, 256, 0, stream>>>(bufB, Wlin, blin, gstart, outp);
}

// Round 6
// 471.445 us; speedup vs baseline: 8.3858x; 1.0568x over previous
//
#include <hip/hip_runtime.h>

#define NN 50000
#define NE 800000
#define NG 256
#define NB ((NN + 255) / 256)   // scan blocks

// ---------- CSR build ----------
__global__ void hist_deg(const int* __restrict__ dst, int* __restrict__ deg) {
    int e = blockIdx.x * blockDim.x + threadIdx.x;
    if (e < NE) atomicAdd(&deg[dst[e]], 1);
}

__global__ void block_scan(const int* __restrict__ deg, int* __restrict__ iscan,
                           int* __restrict__ bsum) {
    __shared__ int sh[256];
    int t = threadIdx.x;
    int i = blockIdx.x * 256 + t;
    int v = (i < NN) ? deg[i] : 0;
    sh[t] = v;
    __syncthreads();
    #pragma unroll
    for (int off = 1; off < 256; off <<= 1) {
        int add = (t >= off) ? sh[t - off] : 0;
        __syncthreads();
        sh[t] += add;
        __syncthreads();
    }
    if (i < NN) iscan[i] = sh[t];
    if (t == 255) bsum[blockIdx.x] = sh[255];
}

__global__ void scan_bsum(const int* __restrict__ bsum, int* __restrict__ boff) {
    __shared__ int sh[256];
    int t = threadIdx.x;
    int v = (t < NB) ? bsum[t] : 0;
    sh[t] = v;
    __syncthreads();
    #pragma unroll
    for (int off = 1; off < 256; off <<= 1) {
        int add = (t >= off) ? sh[t - off] : 0;
        __syncthreads();
        sh[t] += add;
        __syncthreads();
    }
    if (t < NB) boff[t] = sh[t] - v;  // exclusive
}

__global__ void finalize_rowptr(const int* __restrict__ deg, const int* __restrict__ iscan,
                                const int* __restrict__ boff, int* __restrict__ rowptr,
                                int* __restrict__ cur) {
    int i = blockIdx.x * 256 + threadIdx.x;
    if (i < NN) {
        int r = iscan[i] - deg[i] + boff[blockIdx.x];
        rowptr[i] = r;
        cur[i] = r;
    }
    if (i == 0) rowptr[NN] = NE;
}

__global__ void fill_csr(const int* __restrict__ src, const int* __restrict__ dst,
                         int* __restrict__ cur, int* __restrict__ esrc) {
    int e = blockIdx.x * blockDim.x + threadIdx.x;
    if (e >= NE) return;
    int p = atomicAdd(&cur[dst[e]], 1);
    esrc[p] = src[e];
}

// ---------- fused gather + MLP + BN ----------
// Phase 1: gather agg tile (x[node] + sum neighbors) straight into LDS.
//   lane = edge-slot * C4 + chunk: EPI edges in flight per load inst, 4-deep
//   unroll -> up to 4*EPI row-reads outstanding; shfl_xor butterfly combines.
// Phase 2/3: register-tiled GEMM1/GEMM2 + BN as before (MT=32).
template <int DIN, int DOUT, int RELU>
__global__ __launch_bounds__(256) void fused_layer(
        const float* __restrict__ xin, const int* __restrict__ esrc,
        const int* __restrict__ rowptr, float* __restrict__ out,
        const float* __restrict__ W1, const float* __restrict__ b1,
        const float* __restrict__ W2, const float* __restrict__ b2,
        const float* __restrict__ gamma, const float* __restrict__ beta,
        const float* __restrict__ mean, const float* __restrict__ var) {
    constexpr int MT  = 32;
    constexpr int CT  = DOUT / 4;
    constexpr int RT  = 256 / CT;
    constexpr int RPT = MT / RT;
    constexpr int LDI = DIN + 4;
    constexpr int LDM = DOUT + 4;
    constexpr int C4  = DIN / 4;      // float4 chunks per row (32 or 16)
    constexpr int EPI = 64 / C4;      // edges per load instruction (2 or 4)
    __shared__ float sh[MT * LDI];

    const int tid  = threadIdx.x;
    const int wave = tid >> 6, lane = tid & 63;
    const int chunk = lane & (C4 - 1);
    const int esl   = lane / C4;      // edge slot 0..EPI-1
    const int nodeBase = blockIdx.x * MT;
    const float4* x4 = (const float4*)xin;

    // ---- phase 1: gather (8 nodes per wave) ----
    for (int r = wave; r < MT; r += 4) {
        int node = nodeBase + r;
        float4 acc = make_float4(0.f, 0.f, 0.f, 0.f);
        if (node < NN) {
            if (esl == 0) acc = x4[(size_t)node * C4 + chunk];  // self term
            int beg = rowptr[node], end = rowptr[node + 1];
            int cnt = end - beg;
            for (int c = 0; c < cnt; c += 64) {
                int take = min(64, cnt - c);
                int myi = (lane < take) ? esrc[beg + c + lane] : 0;
                int i = 0;
                for (; i + 4 * EPI <= take; i += 4 * EPI) {
                    int s0 = __shfl(myi, i + esl);
                    int s1 = __shfl(myi, i + EPI + esl);
                    int s2 = __shfl(myi, i + 2 * EPI + esl);
                    int s3 = __shfl(myi, i + 3 * EPI + esl);
                    float4 v0 = x4[(size_t)s0 * C4 + chunk];
                    float4 v1 = x4[(size_t)s1 * C4 + chunk];
                    float4 v2 = x4[(size_t)s2 * C4 + chunk];
                    float4 v3 = x4[(size_t)s3 * C4 + chunk];
                    acc.x += (v0.x + v1.x) + (v2.x + v3.x);
                    acc.y += (v0.y + v1.y) + (v2.y + v3.y);
                    acc.z += (v0.z + v1.z) + (v2.z + v3.z);
                    acc.w += (v0.w + v1.w) + (v2.w + v3.w);
                }
                for (; i + EPI <= take; i += EPI) {
                    int s = __shfl(myi, i + esl);
                    float4 v = x4[(size_t)s * C4 + chunk];
                    acc.x += v.x; acc.y += v.y; acc.z += v.z; acc.w += v.w;
                }
                int rem = take - i;
                if (rem > 0) {
                    int s = __shfl(myi, i + ((esl < rem) ? esl : 0));
                    float4 v = x4[(size_t)s * C4 + chunk];
                    if (esl < rem) {
                        acc.x += v.x; acc.y += v.y; acc.z += v.z; acc.w += v.w;
                    }
                }
            }
        }
        // combine edge slots: butterfly over slot bits
        #pragma unroll
        for (int off = 32; off >= C4; off >>= 1) {
            acc.x += __shfl_xor(acc.x, off);
            acc.y += __shfl_xor(acc.y, off);
            acc.z += __shfl_xor(acc.z, off);
            acc.w += __shfl_xor(acc.w, off);
        }
        if (esl == 0)
            *(float4*)&sh[r * LDI + chunk * 4] = acc;  // zeros for OOB rows
    }
    __syncthreads();

    const int colid = tid % CT, rowid = tid / CT;
    const int c0 = colid * 4, r0 = rowid * RPT;
    float acc[RPT][4];

    // ---- GEMM1: h = relu(tile @ W1 + b1) ----
    {
        float4 bv = *(const float4*)&b1[c0];
        #pragma unroll
        for (int i = 0; i < RPT; i++) {
            acc[i][0] = bv.x; acc[i][1] = bv.y; acc[i][2] = bv.z; acc[i][3] = bv.w;
        }
        #pragma unroll 2
        for (int k4 = 0; k4 < DIN / 4; k4++) {
            float4 w[4];
            #pragma unroll
            for (int kk = 0; kk < 4; kk++)
                w[kk] = *(const float4*)&W1[(k4 * 4 + kk) * DOUT + c0];
            #pragma unroll
            for (int i = 0; i < RPT; i++) {
                float4 a = *(const float4*)&sh[(r0 + i) * LDI + k4 * 4];
                const float av[4] = {a.x, a.y, a.z, a.w};
                #pragma unroll
                for (int kk = 0; kk < 4; kk++) {
                    const float* wp = (const float*)&w[kk];
                    #pragma unroll
                    for (int j = 0; j < 4; j++)
                        acc[i][j] = fmaf(av[kk], wp[j], acc[i][j]);
                }
            }
        }
    }
    __syncthreads();
    #pragma unroll
    for (int i = 0; i < RPT; i++) {
        float4 h;
        h.x = fmaxf(acc[i][0], 0.f); h.y = fmaxf(acc[i][1], 0.f);
        h.z = fmaxf(acc[i][2], 0.f); h.w = fmaxf(acc[i][3], 0.f);
        *(float4*)&sh[(r0 + i) * LDM + c0] = h;
    }
    __syncthreads();

    // ---- GEMM2: z = h @ W2 + b2 ----
    {
        float4 bv = *(const float4*)&b2[c0];
        #pragma unroll
        for (int i = 0; i < RPT; i++) {
            acc[i][0] = bv.x; acc[i][1] = bv.y; acc[i][2] = bv.z; acc[i][3] = bv.w;
        }
        #pragma unroll 2
        for (int k4 = 0; k4 < DOUT / 4; k4++) {
            float4 w[4];
            #pragma unroll
            for (int kk = 0; kk < 4; kk++)
                w[kk] = *(const float4*)&W2[(k4 * 4 + kk) * DOUT + c0];
            #pragma unroll
            for (int i = 0; i < RPT; i++) {
                float4 a = *(const float4*)&sh[(r0 + i) * LDM + k4 * 4];
                const float av[4] = {a.x, a.y, a.z, a.w};
                #pragma unroll
                for (int kk = 0; kk < 4; kk++) {
                    const float* wp = (const float*)&w[kk];
                    #pragma unroll
                    for (int j = 0; j < 4; j++)
                        acc[i][j] = fmaf(av[kk], wp[j], acc[i][j]);
                }
            }
        }
    }

    // ---- BN (+ReLU) + store ----
    float4 gv = *(const float4*)&gamma[c0];
    float4 bev = *(const float4*)&beta[c0];
    float4 mv = *(const float4*)&mean[c0];
    float4 vv = *(const float4*)&var[c0];
    float scale[4], shift[4];
    const float* gp = (const float*)&gv; const float* bp = (const float*)&bev;
    const float* mp = (const float*)&mv; const float* vp = (const float*)&vv;
    #pragma unroll
    for (int j = 0; j < 4; j++) {
        scale[j] = gp[j] * (1.0f / sqrtf(vp[j] + 1e-5f));
        shift[j] = bp[j] - mp[j] * scale[j];
    }
    #pragma unroll
    for (int i = 0; i < RPT; i++) {
        int node = nodeBase + r0 + i;
        if (node < NN) {
            float4 o;
            float* op = (float*)&o;
            #pragma unroll
            for (int j = 0; j < 4; j++) {
                float z = fmaf(acc[i][j], scale[j], shift[j]);
                op[j] = RELU ? fmaxf(z, 0.f) : z;
            }
            *(float4*)&out[(size_t)node * DOUT + c0] = o;
        }
    }
}

// ---------- head: graph boundaries (batch is sorted) ----------
__global__ void find_bounds(const int* __restrict__ batch, int* __restrict__ gstart) {
    int n = blockIdx.x * 256 + threadIdx.x;
    if (n >= NN) return;
    int b = batch[n];
    if (n == 0) {
        for (int g = 0; g <= b; g++) gstart[g] = 0;
    } else {
        int p = batch[n - 1];
        for (int g = p + 1; g <= b; g++) gstart[g] = n;
    }
    if (n == NN - 1) {
        for (int g = b + 1; g <= NG; g++) gstart[g] = NN;
    }
}

// one block per graph: logits + max + exp-sum + normalize, no global atomics
__global__ __launch_bounds__(256) void seg_softmax(
        const float* __restrict__ x32, const float* __restrict__ Wl,
        const float* __restrict__ bl, const int* __restrict__ gstart,
        float* __restrict__ out) {
    __shared__ float sWl[32];
    __shared__ float slog[1024];
    __shared__ float sred[4];
    __shared__ float sbc[2];
    int g = blockIdx.x;
    int beg = gstart[g], end = gstart[g + 1];
    int cnt = end - beg;
    int t = threadIdx.x;
    if (cnt <= 0) return;
    if (t < 32) sWl[t] = Wl[t];
    __syncthreads();
    bool fits = (cnt <= 1024);
    float bias = bl[0];

    float lmax = -3.402823466e+38f;
    for (int i = t; i < cnt; i += 256) {
        const float4* xr = (const float4*)(x32 + (size_t)(beg + i) * 32);
        float acc = bias;
        #pragma unroll
        for (int q = 0; q < 8; q++) {
            float4 v = xr[q];
            acc = fmaf(v.x, sWl[q * 4 + 0], acc);
            acc = fmaf(v.y, sWl[q * 4 + 1], acc);
            acc = fmaf(v.z, sWl[q * 4 + 2], acc);
            acc = fmaf(v.w, sWl[q * 4 + 3], acc);
        }
        float lg = acc * 0.2f;
        if (fits) slog[i] = lg;
        lmax = fmaxf(lmax, lg);
    }
    #pragma unroll
    for (int off = 32; off > 0; off >>= 1)
        lmax = fmaxf(lmax, __shfl_down(lmax, off));
    if ((t & 63) == 0) sred[t >> 6] = lmax;
    __syncthreads();
    if (t == 0) sbc[0] = fmaxf(fmaxf(sred[0], sred[1]), fmaxf(sred[2], sred[3]));
    __syncthreads();
    float gm = sbc[0];

    float lsum = 0.f;
    for (int i = t; i < cnt; i += 256) {
        float lg;
        if (fits) lg = slog[i];
        else {
            const float4* xr = (const float4*)(x32 + (size_t)(beg + i) * 32);
            float acc = bias;
            #pragma unroll
            for (int q = 0; q < 8; q++) {
                float4 v = xr[q];
                acc = fmaf(v.x, sWl[q * 4 + 0], acc);
                acc = fmaf(v.y, sWl[q * 4 + 1], acc);
                acc = fmaf(v.z, sWl[q * 4 + 2], acc);
                acc = fmaf(v.w, sWl[q * 4 + 3], acc);
            }
            lg = acc * 0.2f;
        }
        float e = expf(lg - gm);
        if (fits) slog[i] = e;
        lsum += e;
    }
    #pragma unroll
    for (int off = 32; off > 0; off >>= 1)
        lsum += __shfl_down(lsum, off);
    __syncthreads();
    if ((t & 63) == 0) sred[t >> 6] = lsum;
    __syncthreads();
    if (t == 0) sbc[1] = (sred[0] + sred[1]) + (sred[2] + sred[3]);
    __syncthreads();
    float inv = 1.0f / sbc[1];

    for (int i = t; i < cnt; i += 256) {
        float e;
        if (fits) e = slog[i];
        else {
            const float4* xr = (const float4*)(x32 + (size_t)(beg + i) * 32);
            float acc = bias;
            #pragma unroll
            for (int q = 0; q < 8; q++) {
                float4 v = xr[q];
                acc = fmaf(v.x, sWl[q * 4 + 0], acc);
                acc = fmaf(v.y, sWl[q * 4 + 1], acc);
                acc = fmaf(v.z, sWl[q * 4 + 2], acc);
                acc = fmaf(v.w, sWl[q * 4 + 3], acc);
            }
            e = expf(acc * 0.2f - gm);
        }
        out[beg + i] = e * inv;
    }
}

// ---------- launch ----------
extern "C" void kernel_launch(void* const* d_in, const int* in_sizes, int n_in,
                              void* d_out, int out_size, void* d_ws, size_t ws_size,
                              hipStream_t stream) {
    const float* x    = (const float*)d_in[0];
    const int*   ei   = (const int*)d_in[1];
    const int*   srcI = ei;
    const int*   dstI = ei + NE;
    const int*   batch = (const int*)d_in[2];

    const float* P[29];
    for (int i = 0; i < 29; i++) P[i] = (const float*)d_in[i];
    const float* Wlin = P[27];
    const float* blin = P[28];

    float* bufA = (float*)d_ws;              // N x 128 ping
    float* bufB = bufA + (size_t)NN * 128;   // N x 128 pong
    int* gstart = (int*)(bufB + (size_t)NN * 128);  // NG+1
    int* deg    = gstart + NG + 1;               // N
    int* iscan  = deg + NN;                      // N
    int* rowptr = iscan + NN;                    // N+1
    int* cur    = rowptr + NN + 1;               // N
    int* bsum   = cur + NN;                      // NB
    int* boff   = bsum + NB;                     // NB
    int* esrc   = boff + NB;                     // E
    float* outp = (float*)d_out;

    const int TB = 256;

    // ---- build CSR ----
    hipMemsetAsync(deg, 0, NN * sizeof(int), stream);
    hist_deg<<<(NE + TB - 1) / TB, TB, 0, stream>>>(dstI, deg);
    block_scan<<<NB, 256, 0, stream>>>(deg, iscan, bsum);
    scan_bsum<<<1, 256, 0, stream>>>(bsum, boff);
    finalize_rowptr<<<NB, 256, 0, stream>>>(deg, iscan, boff, rowptr, cur);
    fill_csr<<<(NE + TB - 1) / TB, TB, 0, stream>>>(srcI, dstI, cur, esrc);

    find_bounds<<<NB, 256, 0, stream>>>(batch, gstart);

    const int FUSED_BLOCKS = (NN + 31) / 32;

    // ---- fused layers ----
    fused_layer<128, 128, 1><<<FUSED_BLOCKS, 256, 0, stream>>>(
        x, esrc, rowptr, bufA, P[3], P[4], P[5], P[6], P[7], P[8], P[9], P[10]);
    fused_layer<128, 64, 1><<<FUSED_BLOCKS, 256, 0, stream>>>(
        bufA, esrc, rowptr, bufB, P[11], P[12], P[13], P[14], P[15], P[16], P[17], P[18]);
    fused_layer<64, 32, 0><<<FUSED_BLOCKS, 256, 0, stream>>>(
        bufB, esrc, rowptr, bufA, P[19], P[20], P[21], P[22], P[23], P[24], P[25], P[26]);

    // ---- head ----
    seg_softmax<<<NG, 256, 0, stream>>>(bufA, Wlin, blin, gstart, outp);
}

// Round 7
// 429.938 us; speedup vs baseline: 9.1953x; 1.0965x over previous
//
#include <hip/hip_runtime.h>

#define NN 50000
#define NE 800000
#define NG 256
#define NB ((NN + 255) / 256)   // scan blocks

// ---------- CSR build ----------
__global__ void hist_deg(const int* __restrict__ dst, int* __restrict__ deg) {
    int e = blockIdx.x * blockDim.x + threadIdx.x;
    if (e < NE) atomicAdd(&deg[dst[e]], 1);
}

__global__ void block_scan(const int* __restrict__ deg, int* __restrict__ iscan,
                           int* __restrict__ bsum) {
    __shared__ int sh[256];
    int t = threadIdx.x;
    int i = blockIdx.x * 256 + t;
    int v = (i < NN) ? deg[i] : 0;
    sh[t] = v;
    __syncthreads();
    #pragma unroll
    for (int off = 1; off < 256; off <<= 1) {
        int add = (t >= off) ? sh[t - off] : 0;
        __syncthreads();
        sh[t] += add;
        __syncthreads();
    }
    if (i < NN) iscan[i] = sh[t];
    if (t == 255) bsum[blockIdx.x] = sh[255];
}

__global__ void scan_bsum(const int* __restrict__ bsum, int* __restrict__ boff) {
    __shared__ int sh[256];
    int t = threadIdx.x;
    int v = (t < NB) ? bsum[t] : 0;
    sh[t] = v;
    __syncthreads();
    #pragma unroll
    for (int off = 1; off < 256; off <<= 1) {
        int add = (t >= off) ? sh[t - off] : 0;
        __syncthreads();
        sh[t] += add;
        __syncthreads();
    }
    if (t < NB) boff[t] = sh[t] - v;  // exclusive
}

__global__ void finalize_rowptr(const int* __restrict__ deg, const int* __restrict__ iscan,
                                const int* __restrict__ boff, int* __restrict__ rowptr,
                                int* __restrict__ cur) {
    int i = blockIdx.x * 256 + threadIdx.x;
    if (i < NN) {
        int r = iscan[i] - deg[i] + boff[blockIdx.x];
        rowptr[i] = r;
        cur[i] = r;
    }
    if (i == 0) rowptr[NN] = NE;
}

__global__ void fill_csr(const int* __restrict__ src, const int* __restrict__ dst,
                         int* __restrict__ cur, int* __restrict__ esrc) {
    int e = blockIdx.x * blockDim.x + threadIdx.x;
    if (e >= NE) return;
    int p = atomicAdd(&cur[dst[e]], 1);
    esrc[p] = src[e];
}

// ---------- wave-cooperative gather of one node row ----------
// lane = esl*C4 + chunk; EPI edges per load inst, 4-deep unroll; butterfly
// combine over edge slots. Valid on lanes with esl==0 (lane < C4).
template <int DIN>
__device__ __forceinline__ float4 gather_node(const float4* __restrict__ x4,
                                              const int* __restrict__ esrc,
                                              int beg, int cnt, int node, int lane) {
    constexpr int C4  = DIN / 4;
    constexpr int EPI = 64 / C4;
    const int chunk = lane & (C4 - 1);
    const int esl   = lane / C4;
    float4 acc = make_float4(0.f, 0.f, 0.f, 0.f);
    if (esl == 0) acc = x4[(size_t)node * C4 + chunk];  // self term
    for (int c = 0; c < cnt; c += 64) {
        int take = min(64, cnt - c);
        int myi = (lane < take) ? esrc[beg + c + lane] : 0;
        int i = 0;
        for (; i + 4 * EPI <= take; i += 4 * EPI) {
            int s0 = __shfl(myi, i + esl);
            int s1 = __shfl(myi, i + EPI + esl);
            int s2 = __shfl(myi, i + 2 * EPI + esl);
            int s3 = __shfl(myi, i + 3 * EPI + esl);
            float4 v0 = x4[(size_t)s0 * C4 + chunk];
            float4 v1 = x4[(size_t)s1 * C4 + chunk];
            float4 v2 = x4[(size_t)s2 * C4 + chunk];
            float4 v3 = x4[(size_t)s3 * C4 + chunk];
            acc.x += (v0.x + v1.x) + (v2.x + v3.x);
            acc.y += (v0.y + v1.y) + (v2.y + v3.y);
            acc.z += (v0.z + v1.z) + (v2.z + v3.z);
            acc.w += (v0.w + v1.w) + (v2.w + v3.w);
        }
        for (; i + EPI <= take; i += EPI) {
            int s = __shfl(myi, i + esl);
            float4 v = x4[(size_t)s * C4 + chunk];
            acc.x += v.x; acc.y += v.y; acc.z += v.z; acc.w += v.w;
        }
        int rem = take - i;
        if (rem > 0) {
            int s = __shfl(myi, i + ((esl < rem) ? esl : 0));
            float4 v = x4[(size_t)s * C4 + chunk];
            if (esl < rem) {
                acc.x += v.x; acc.y += v.y; acc.z += v.z; acc.w += v.w;
            }
        }
    }
    #pragma unroll
    for (int off = 32; off >= C4; off >>= 1) {
        acc.x += __shfl_xor(acc.x, off);
        acc.y += __shfl_xor(acc.y, off);
        acc.z += __shfl_xor(acc.z, off);
        acc.w += __shfl_xor(acc.w, off);
    }
    return acc;
}

// ---------- fused layer 0: gather x(128) -> MLP0+BN+relu -> xW1_1 -> z1(N x 64) ----------
__global__ __launch_bounds__(256) void fused_L0(
        const float* __restrict__ xin, const int* __restrict__ esrc,
        const int* __restrict__ rowptr, float* __restrict__ z1,
        const float* __restrict__ W1, const float* __restrict__ b1,
        const float* __restrict__ W2, const float* __restrict__ b2,
        const float* __restrict__ gamma, const float* __restrict__ beta,
        const float* __restrict__ mean, const float* __restrict__ var,
        const float* __restrict__ Wn /* W1_1: 128x64 */) {
    constexpr int MT = 32, LD = 132;
    __shared__ float sh[MT * LD];
    const int tid = threadIdx.x, wave = tid >> 6, lane = tid & 63;
    const int nodeBase = blockIdx.x * MT;

    // phase 1: gather
    for (int r = wave; r < MT; r += 4) {
        int node = nodeBase + r;
        float4 acc = make_float4(0.f, 0.f, 0.f, 0.f);
        if (node < NN) {
            int beg = rowptr[node], end = rowptr[node + 1];
            acc = gather_node<128>((const float4*)xin, esrc, beg, end - beg, node, lane);
        }
        if (lane < 32) *(float4*)&sh[r * LD + lane * 4] = acc;
    }
    __syncthreads();

    // GEMM1: 128->128, relu
    const int colid = tid % 32, rowid = tid / 32;      // CT=32, RT=8
    const int c0 = colid * 4, r0 = rowid * 4;          // RPT=4
    float acc[4][4];
    {
        float4 bv = *(const float4*)&b1[c0];
        #pragma unroll
        for (int i = 0; i < 4; i++) {
            acc[i][0] = bv.x; acc[i][1] = bv.y; acc[i][2] = bv.z; acc[i][3] = bv.w;
        }
        #pragma unroll 2
        for (int k4 = 0; k4 < 32; k4++) {
            float4 w[4];
            #pragma unroll
            for (int kk = 0; kk < 4; kk++)
                w[kk] = *(const float4*)&W1[(k4 * 4 + kk) * 128 + c0];
            #pragma unroll
            for (int i = 0; i < 4; i++) {
                float4 a = *(const float4*)&sh[(r0 + i) * LD + k4 * 4];
                const float av[4] = {a.x, a.y, a.z, a.w};
                #pragma unroll
                for (int kk = 0; kk < 4; kk++) {
                    const float* wp = (const float*)&w[kk];
                    #pragma unroll
                    for (int j = 0; j < 4; j++)
                        acc[i][j] = fmaf(av[kk], wp[j], acc[i][j]);
                }
            }
        }
    }
    __syncthreads();
    #pragma unroll
    for (int i = 0; i < 4; i++) {
        float4 h;
        h.x = fmaxf(acc[i][0], 0.f); h.y = fmaxf(acc[i][1], 0.f);
        h.z = fmaxf(acc[i][2], 0.f); h.w = fmaxf(acc[i][3], 0.f);
        *(float4*)&sh[(r0 + i) * LD + c0] = h;
    }
    __syncthreads();

    // GEMM2: 128->128, BN, relu
    {
        float4 bv = *(const float4*)&b2[c0];
        #pragma unroll
        for (int i = 0; i < 4; i++) {
            acc[i][0] = bv.x; acc[i][1] = bv.y; acc[i][2] = bv.z; acc[i][3] = bv.w;
        }
        #pragma unroll 2
        for (int k4 = 0; k4 < 32; k4++) {
            float4 w[4];
            #pragma unroll
            for (int kk = 0; kk < 4; kk++)
                w[kk] = *(const float4*)&W2[(k4 * 4 + kk) * 128 + c0];
            #pragma unroll
            for (int i = 0; i < 4; i++) {
                float4 a = *(const float4*)&sh[(r0 + i) * LD + k4 * 4];
                const float av[4] = {a.x, a.y, a.z, a.w};
                #pragma unroll
                for (int kk = 0; kk < 4; kk++) {
                    const float* wp = (const float*)&w[kk];
                    #pragma unroll
                    for (int j = 0; j < 4; j++)
                        acc[i][j] = fmaf(av[kk], wp[j], acc[i][j]);
                }
            }
        }
    }
    float4 gv = *(const float4*)&gamma[c0];
    float4 bev = *(const float4*)&beta[c0];
    float4 mv = *(const float4*)&mean[c0];
    float4 vv = *(const float4*)&var[c0];
    float scale[4], shift[4];
    {
        const float* gp = (const float*)&gv; const float* bp = (const float*)&bev;
        const float* mp = (const float*)&mv; const float* vp = (const float*)&vv;
        #pragma unroll
        for (int j = 0; j < 4; j++) {
            scale[j] = gp[j] * (1.0f / sqrtf(vp[j] + 1e-5f));
            shift[j] = bp[j] - mp[j] * scale[j];
        }
    }
    __syncthreads();
    #pragma unroll
    for (int i = 0; i < 4; i++) {
        float4 y;
        y.x = fmaxf(fmaf(acc[i][0], scale[0], shift[0]), 0.f);
        y.y = fmaxf(fmaf(acc[i][1], scale[1], shift[1]), 0.f);
        y.z = fmaxf(fmaf(acc[i][2], scale[2], shift[2]), 0.f);
        y.w = fmaxf(fmaf(acc[i][3], scale[3], shift[3]), 0.f);
        *(float4*)&sh[(r0 + i) * LD + c0] = y;
    }
    __syncthreads();

    // GEMM3: y(128) @ W1_1(128x64) -> z1
    {
        const int colid2 = tid % 16, rowid2 = tid / 16;   // CT=16, RT=16
        const int c0b = colid2 * 4, r0b = rowid2 * 2;     // RPT=2
        float a3[2][4] = {};
        #pragma unroll 2
        for (int k4 = 0; k4 < 32; k4++) {
            float4 w[4];
            #pragma unroll
            for (int kk = 0; kk < 4; kk++)
                w[kk] = *(const float4*)&Wn[(k4 * 4 + kk) * 64 + c0b];
            #pragma unroll
            for (int i = 0; i < 2; i++) {
                float4 a = *(const float4*)&sh[(r0b + i) * LD + k4 * 4];
                const float av[4] = {a.x, a.y, a.z, a.w};
                #pragma unroll
                for (int kk = 0; kk < 4; kk++) {
                    const float* wp = (const float*)&w[kk];
                    #pragma unroll
                    for (int j = 0; j < 4; j++)
                        a3[i][j] = fmaf(av[kk], wp[j], a3[i][j]);
                }
            }
        }
        #pragma unroll
        for (int i = 0; i < 2; i++) {
            int node = nodeBase + r0b + i;
            if (node < NN)
                *(float4*)&z1[(size_t)node * 64 + c0b] =
                    make_float4(a3[i][0], a3[i][1], a3[i][2], a3[i][3]);
        }
    }
}

// ---------- fused layer 1: gather z1(64) -> +b1,relu -> W2_1+BN+relu -> xW1_2 -> z2(N x 32) ----------
__global__ __launch_bounds__(256) void fused_L1(
        const float* __restrict__ z1in, const int* __restrict__ esrc,
        const int* __restrict__ rowptr, float* __restrict__ z2,
        const float* __restrict__ b1, const float* __restrict__ W2,
        const float* __restrict__ b2, const float* __restrict__ gamma,
        const float* __restrict__ beta, const float* __restrict__ mean,
        const float* __restrict__ var, const float* __restrict__ Wn /* W1_2: 64x32 */) {
    constexpr int MT = 32, LD = 68;
    __shared__ float sh[MT * LD];
    const int tid = threadIdx.x, wave = tid >> 6, lane = tid & 63;
    const int nodeBase = blockIdx.x * MT;

    // phase 1: gather + bias + relu (h1 = relu(agg + b1))
    for (int r = wave; r < MT; r += 4) {
        int node = nodeBase + r;
        float4 acc = make_float4(0.f, 0.f, 0.f, 0.f);
        if (node < NN) {
            int beg = rowptr[node], end = rowptr[node + 1];
            acc = gather_node<64>((const float4*)z1in, esrc, beg, end - beg, node, lane);
        }
        if (lane < 16) {
            float4 bv = *(const float4*)&b1[lane * 4];
            float4 h;
            h.x = fmaxf(acc.x + bv.x, 0.f); h.y = fmaxf(acc.y + bv.y, 0.f);
            h.z = fmaxf(acc.z + bv.z, 0.f); h.w = fmaxf(acc.w + bv.w, 0.f);
            *(float4*)&sh[r * LD + lane * 4] = h;
        }
    }
    __syncthreads();

    // GEMM_A: 64->64 (W2_1) + BN + relu
    const int colid = tid % 16, rowid = tid / 16;  // CT=16, RT=16
    const int c0 = colid * 4, r0 = rowid * 2;      // RPT=2
    float acc[2][4];
    {
        float4 bv = *(const float4*)&b2[c0];
        #pragma unroll
        for (int i = 0; i < 2; i++) {
            acc[i][0] = bv.x; acc[i][1] = bv.y; acc[i][2] = bv.z; acc[i][3] = bv.w;
        }
        #pragma unroll 2
        for (int k4 = 0; k4 < 16; k4++) {
            float4 w[4];
            #pragma unroll
            for (int kk = 0; kk < 4; kk++)
                w[kk] = *(const float4*)&W2[(k4 * 4 + kk) * 64 + c0];
            #pragma unroll
            for (int i = 0; i < 2; i++) {
                float4 a = *(const float4*)&sh[(r0 + i) * LD + k4 * 4];
                const float av[4] = {a.x, a.y, a.z, a.w};
                #pragma unroll
                for (int kk = 0; kk < 4; kk++) {
                    const float* wp = (const float*)&w[kk];
                    #pragma unroll
                    for (int j = 0; j < 4; j++)
                        acc[i][j] = fmaf(av[kk], wp[j], acc[i][j]);
                }
            }
        }
    }
    float4 gv = *(const float4*)&gamma[c0];
    float4 bev = *(const float4*)&beta[c0];
    float4 mv = *(const float4*)&mean[c0];
    float4 vv = *(const float4*)&var[c0];
    float scale[4], shift[4];
    {
        const float* gp = (const float*)&gv; const float* bp = (const float*)&bev;
        const float* mp = (const float*)&mv; const float* vp = (const float*)&vv;
        #pragma unroll
        for (int j = 0; j < 4; j++) {
            scale[j] = gp[j] * (1.0f / sqrtf(vp[j] + 1e-5f));
            shift[j] = bp[j] - mp[j] * scale[j];
        }
    }
    __syncthreads();
    #pragma unroll
    for (int i = 0; i < 2; i++) {
        float4 y;
        y.x = fmaxf(fmaf(acc[i][0], scale[0], shift[0]), 0.f);
        y.y = fmaxf(fmaf(acc[i][1], scale[1], shift[1]), 0.f);
        y.z = fmaxf(fmaf(acc[i][2], scale[2], shift[2]), 0.f);
        y.w = fmaxf(fmaf(acc[i][3], scale[3], shift[3]), 0.f);
        *(float4*)&sh[(r0 + i) * LD + c0] = y;
    }
    __syncthreads();

    // GEMM_B: y(64) @ W1_2(64x32) -> z2
    {
        const int colid2 = tid % 8, rowid2 = tid / 8;   // CT=8, RT=32, RPT=1
        const int c0b = colid2 * 4, r0b = rowid2;
        float a3[4] = {};
        #pragma unroll 2
        for (int k4 = 0; k4 < 16; k4++) {
            float4 w[4];
            #pragma unroll
            for (int kk = 0; kk < 4; kk++)
                w[kk] = *(const float4*)&Wn[(k4 * 4 + kk) * 32 + c0b];
            float4 a = *(const float4*)&sh[r0b * LD + k4 * 4];
            const float av[4] = {a.x, a.y, a.z, a.w};
            #pragma unroll
            for (int kk = 0; kk < 4; kk++) {
                const float* wp = (const float*)&w[kk];
                #pragma unroll
                for (int j = 0; j < 4; j++)
                    a3[j] = fmaf(av[kk], wp[j], a3[j]);
            }
        }
        int node = nodeBase + r0b;
        if (node < NN)
            *(float4*)&z2[(size_t)node * 32 + c0b] =
                make_float4(a3[0], a3[1], a3[2], a3[3]);
    }
}

// ---------- fused layer 2: gather z2(32) -> +b1,relu -> W2_2+BN -> xW_lin -> logits(N) ----------
__global__ __launch_bounds__(256) void fused_L2(
        const float* __restrict__ z2in, const int* __restrict__ esrc,
        const int* __restrict__ rowptr, float* __restrict__ logits,
        const float* __restrict__ b1, const float* __restrict__ W2,
        const float* __restrict__ b2, const float* __restrict__ gamma,
        const float* __restrict__ beta, const float* __restrict__ mean,
        const float* __restrict__ var, const float* __restrict__ Wl,
        const float* __restrict__ bl) {
    constexpr int MT = 32, LD = 36;
    __shared__ float sh[MT * LD];
    const int tid = threadIdx.x, wave = tid >> 6, lane = tid & 63;
    const int nodeBase = blockIdx.x * MT;

    for (int r = wave; r < MT; r += 4) {
        int node = nodeBase + r;
        float4 acc = make_float4(0.f, 0.f, 0.f, 0.f);
        if (node < NN) {
            int beg = rowptr[node], end = rowptr[node + 1];
            acc = gather_node<32>((const float4*)z2in, esrc, beg, end - beg, node, lane);
        }
        if (lane < 8) {
            float4 bv = *(const float4*)&b1[lane * 4];
            float4 h;
            h.x = fmaxf(acc.x + bv.x, 0.f); h.y = fmaxf(acc.y + bv.y, 0.f);
            h.z = fmaxf(acc.z + bv.z, 0.f); h.w = fmaxf(acc.w + bv.w, 0.f);
            *(float4*)&sh[r * LD + lane * 4] = h;
        }
    }
    __syncthreads();

    // GEMM: 32->32 (W2_2) + BN (no relu), then dot with W_lin
    const int colid = tid % 8, rowid = tid / 8;   // CT=8, RT=32, RPT=1
    const int c0 = colid * 4, r0 = rowid;
    float acc[4];
    {
        float4 bv = *(const float4*)&b2[c0];
        acc[0] = bv.x; acc[1] = bv.y; acc[2] = bv.z; acc[3] = bv.w;
        #pragma unroll
        for (int k4 = 0; k4 < 8; k4++) {
            float4 w[4];
            #pragma unroll
            for (int kk = 0; kk < 4; kk++)
                w[kk] = *(const float4*)&W2[(k4 * 4 + kk) * 32 + c0];
            float4 a = *(const float4*)&sh[r0 * LD + k4 * 4];
            const float av[4] = {a.x, a.y, a.z, a.w};
            #pragma unroll
            for (int kk = 0; kk < 4; kk++) {
                const float* wp = (const float*)&w[kk];
                #pragma unroll
                for (int j = 0; j < 4; j++)
                    acc[j] = fmaf(av[kk], wp[j], acc[j]);
            }
        }
    }
    float4 gv = *(const float4*)&gamma[c0];
    float4 bev = *(const float4*)&beta[c0];
    float4 mv = *(const float4*)&mean[c0];
    float4 vv = *(const float4*)&var[c0];
    float4 wl = *(const float4*)&Wl[c0];
    float p = 0.f;
    {
        const float* gp = (const float*)&gv; const float* bp = (const float*)&bev;
        const float* mp = (const float*)&mv; const float* vp = (const float*)&vv;
        const float* wp = (const float*)&wl;
        #pragma unroll
        for (int j = 0; j < 4; j++) {
            float sc = gp[j] * (1.0f / sqrtf(vp[j] + 1e-5f));
            float y = (acc[j] - mp[j]) * sc + bp[j];
            p = fmaf(y, wp[j], p);
        }
    }
    // reduce across the 8 threads sharing a node (consecutive lanes)
    p += __shfl_xor(p, 1);
    p += __shfl_xor(p, 2);
    p += __shfl_xor(p, 4);
    int node = nodeBase + r0;
    if ((tid & 7) == 0 && node < NN)
        logits[node] = (p + bl[0]) * 0.2f;
}

// ---------- head ----------
__global__ void find_bounds(const int* __restrict__ batch, int* __restrict__ gstart) {
    int n = blockIdx.x * 256 + threadIdx.x;
    if (n >= NN) return;
    int b = batch[n];
    if (n == 0) {
        for (int g = 0; g <= b; g++) gstart[g] = 0;
    } else {
        int p = batch[n - 1];
        for (int g = p + 1; g <= b; g++) gstart[g] = n;
    }
    if (n == NN - 1) {
        for (int g = b + 1; g <= NG; g++) gstart[g] = NN;
    }
}

__global__ __launch_bounds__(256) void seg_softmax(
        const float* __restrict__ logits, const int* __restrict__ gstart,
        float* __restrict__ out) {
    __shared__ float slog[1024];
    __shared__ float sred[4];
    __shared__ float sbc[2];
    int g = blockIdx.x;
    int beg = gstart[g], end = gstart[g + 1];
    int cnt = end - beg;
    int t = threadIdx.x;
    if (cnt <= 0) return;
    bool fits = (cnt <= 1024);

    float lmax = -3.402823466e+38f;
    for (int i = t; i < cnt; i += 256) {
        float lg = logits[beg + i];
        if (fits) slog[i] = lg;
        lmax = fmaxf(lmax, lg);
    }
    #pragma unroll
    for (int off = 32; off > 0; off >>= 1)
        lmax = fmaxf(lmax, __shfl_down(lmax, off));
    if ((t & 63) == 0) sred[t >> 6] = lmax;
    __syncthreads();
    if (t == 0) sbc[0] = fmaxf(fmaxf(sred[0], sred[1]), fmaxf(sred[2], sred[3]));
    __syncthreads();
    float gm = sbc[0];

    float lsum = 0.f;
    for (int i = t; i < cnt; i += 256) {
        float lg = fits ? slog[i] : logits[beg + i];
        float e = expf(lg - gm);
        if (fits) slog[i] = e;
        lsum += e;
    }
    #pragma unroll
    for (int off = 32; off > 0; off >>= 1)
        lsum += __shfl_down(lsum, off);
    __syncthreads();
    if ((t & 63) == 0) sred[t >> 6] = lsum;
    __syncthreads();
    if (t == 0) sbc[1] = (sred[0] + sred[1]) + (sred[2] + sred[3]);
    __syncthreads();
    float inv = 1.0f / sbc[1];

    for (int i = t; i < cnt; i += 256) {
        float e = fits ? slog[i] : expf(logits[beg + i] - gm);
        out[beg + i] = e * inv;
    }
}

// ---------- launch ----------
extern "C" void kernel_launch(void* const* d_in, const int* in_sizes, int n_in,
                              void* d_out, int out_size, void* d_ws, size_t ws_size,
                              hipStream_t stream) {
    const float* x    = (const float*)d_in[0];
    const int*   ei   = (const int*)d_in[1];
    const int*   srcI = ei;
    const int*   dstI = ei + NE;
    const int*   batch = (const int*)d_in[2];

    const float* P[29];
    for (int i = 0; i < 29; i++) P[i] = (const float*)d_in[i];
    const float* Wlin = P[27];
    const float* blin = P[28];

    float* z1     = (float*)d_ws;            // N x 64
    float* z2     = z1 + (size_t)NN * 64;    // N x 32
    float* logits = z2 + (size_t)NN * 32;    // N
    int* gstart = (int*)(logits + NN);       // NG+1
    int* deg    = gstart + NG + 1;           // N
    int* iscan  = deg + NN;                  // N
    int* rowptr = iscan + NN;                // N+1
    int* cur    = rowptr + NN + 1;           // N
    int* bsum   = cur + NN;                  // NB
    int* boff   = bsum + NB;                 // NB
    int* esrc   = boff + NB;                 // E
    float* outp = (float*)d_out;

    const int TB = 256;

    // ---- build CSR ----
    hipMemsetAsync(deg, 0, NN * sizeof(int), stream);
    hist_deg<<<(NE + TB - 1) / TB, TB, 0, stream>>>(dstI, deg);
    block_scan<<<NB, 256, 0, stream>>>(deg, iscan, bsum);
    scan_bsum<<<1, 256, 0, stream>>>(bsum, boff);
    finalize_rowptr<<<NB, 256, 0, stream>>>(deg, iscan, boff, rowptr, cur);
    fill_csr<<<(NE + TB - 1) / TB, TB, 0, stream>>>(srcI, dstI, cur, esrc);

    find_bounds<<<NB, 256, 0, stream>>>(batch, gstart);

    const int FB = (NN + 31) / 32;

    fused_L0<<<FB, 256, 0, stream>>>(x, esrc, rowptr, z1,
        P[3], P[4], P[5], P[6], P[7], P[8], P[9], P[10], P[11]);
    fused_L1<<<FB, 256, 0, stream>>>(z1, esrc, rowptr, z2,
        P[12], P[13], P[14], P[15], P[16], P[17], P[18], P[19]);
    fused_L2<<<FB, 256, 0, stream>>>(z2, esrc, rowptr, logits,
        P[20], P[21], P[22], P[23], P[24], P[25], P[26], Wlin, blin);

    seg_softmax<<<NG, 256, 0, stream>>>(logits, gstart, outp);
}

// Round 8
// 421.875 us; speedup vs baseline: 9.3711x; 1.0191x over previous
//
#include <hip/hip_runtime.h>

#define NN 50000
#define NE 800000
#define NG 256
#define NB ((NN + 255) / 256)   // scan blocks

// ---------- bf16 helpers ----------
__device__ __forceinline__ unsigned short f2bf_rne(float f) {
    unsigned u = __float_as_uint(f);
    u += 0x7fffu + ((u >> 16) & 1u);   // round-to-nearest-even
    return (unsigned short)(u >> 16);
}
#define BF2F_LO(u) __uint_as_float((u) << 16)
#define BF2F_HI(u) __uint_as_float((u) & 0xffff0000u)

__global__ void x_to_bf16(const float4* __restrict__ x, ushort4* __restrict__ xh, int n4) {
    int i = blockIdx.x * 256 + threadIdx.x;
    if (i < n4) {
        float4 v = x[i];
        ushort4 o;
        o.x = f2bf_rne(v.x); o.y = f2bf_rne(v.y);
        o.z = f2bf_rne(v.z); o.w = f2bf_rne(v.w);
        xh[i] = o;
    }
}

// ---------- CSR build ----------
__global__ void hist_deg(const int* __restrict__ dst, int* __restrict__ deg) {
    int e = blockIdx.x * blockDim.x + threadIdx.x;
    if (e < NE) atomicAdd(&deg[dst[e]], 1);
}

__global__ void block_scan(const int* __restrict__ deg, int* __restrict__ iscan,
                           int* __restrict__ bsum) {
    __shared__ int sh[256];
    int t = threadIdx.x;
    int i = blockIdx.x * 256 + t;
    int v = (i < NN) ? deg[i] : 0;
    sh[t] = v;
    __syncthreads();
    #pragma unroll
    for (int off = 1; off < 256; off <<= 1) {
        int add = (t >= off) ? sh[t - off] : 0;
        __syncthreads();
        sh[t] += add;
        __syncthreads();
    }
    if (i < NN) iscan[i] = sh[t];
    if (t == 255) bsum[blockIdx.x] = sh[255];
}

__global__ void scan_bsum(const int* __restrict__ bsum, int* __restrict__ boff) {
    __shared__ int sh[256];
    int t = threadIdx.x;
    int v = (t < NB) ? bsum[t] : 0;
    sh[t] = v;
    __syncthreads();
    #pragma unroll
    for (int off = 1; off < 256; off <<= 1) {
        int add = (t >= off) ? sh[t - off] : 0;
        __syncthreads();
        sh[t] += add;
        __syncthreads();
    }
    if (t < NB) boff[t] = sh[t] - v;  // exclusive
}

__global__ void finalize_rowptr(const int* __restrict__ deg, const int* __restrict__ iscan,
                                const int* __restrict__ boff, int* __restrict__ rowptr,
                                int* __restrict__ cur) {
    int i = blockIdx.x * 256 + threadIdx.x;
    if (i < NN) {
        int r = iscan[i] - deg[i] + boff[blockIdx.x];
        rowptr[i] = r;
        cur[i] = r;
    }
    if (i == 0) rowptr[NN] = NE;
}

__global__ void fill_csr(const int* __restrict__ src, const int* __restrict__ dst,
                         int* __restrict__ cur, int* __restrict__ esrc) {
    int e = blockIdx.x * blockDim.x + threadIdx.x;
    if (e >= NE) return;
    int p = atomicAdd(&cur[dst[e]], 1);
    esrc[p] = src[e];
}

// ---------- fp32 wave-cooperative gather (used for 64/32-wide layers) ----------
template <int DIN>
__device__ __forceinline__ float4 gather_node(const float4* __restrict__ x4,
                                              const int* __restrict__ esrc,
                                              int beg, int cnt, int node, int lane) {
    constexpr int C4  = DIN / 4;
    constexpr int EPI = 64 / C4;
    const int chunk = lane & (C4 - 1);
    const int esl   = lane / C4;
    float4 acc = make_float4(0.f, 0.f, 0.f, 0.f);
    if (esl == 0) acc = x4[(size_t)node * C4 + chunk];  // self term
    for (int c = 0; c < cnt; c += 64) {
        int take = min(64, cnt - c);
        int myi = (lane < take) ? esrc[beg + c + lane] : 0;
        int i = 0;
        for (; i + 4 * EPI <= take; i += 4 * EPI) {
            int s0 = __shfl(myi, i + esl);
            int s1 = __shfl(myi, i + EPI + esl);
            int s2 = __shfl(myi, i + 2 * EPI + esl);
            int s3 = __shfl(myi, i + 3 * EPI + esl);
            float4 v0 = x4[(size_t)s0 * C4 + chunk];
            float4 v1 = x4[(size_t)s1 * C4 + chunk];
            float4 v2 = x4[(size_t)s2 * C4 + chunk];
            float4 v3 = x4[(size_t)s3 * C4 + chunk];
            acc.x += (v0.x + v1.x) + (v2.x + v3.x);
            acc.y += (v0.y + v1.y) + (v2.y + v3.y);
            acc.z += (v0.z + v1.z) + (v2.z + v3.z);
            acc.w += (v0.w + v1.w) + (v2.w + v3.w);
        }
        for (; i + EPI <= take; i += EPI) {
            int s = __shfl(myi, i + esl);
            float4 v = x4[(size_t)s * C4 + chunk];
            acc.x += v.x; acc.y += v.y; acc.z += v.z; acc.w += v.w;
        }
        int rem = take - i;
        if (rem > 0) {
            int s = __shfl(myi, i + ((esl < rem) ? esl : 0));
            float4 v = x4[(size_t)s * C4 + chunk];
            if (esl < rem) {
                acc.x += v.x; acc.y += v.y; acc.z += v.z; acc.w += v.w;
            }
        }
    }
    #pragma unroll
    for (int off = 32; off >= C4; off >>= 1) {
        acc.x += __shfl_xor(acc.x, off);
        acc.y += __shfl_xor(acc.y, off);
        acc.z += __shfl_xor(acc.z, off);
        acc.w += __shfl_xor(acc.w, off);
    }
    return acc;
}

// ---------- fused layer 0: bf16 gather x(128) -> MLP0+BN+relu -> xW1_1 -> z1(N x 64) ----------
__global__ __launch_bounds__(256) void fused_L0(
        const unsigned short* __restrict__ xh, const int* __restrict__ esrc,
        const int* __restrict__ rowptr, float* __restrict__ z1,
        const float* __restrict__ W1, const float* __restrict__ b1,
        const float* __restrict__ W2, const float* __restrict__ b2,
        const float* __restrict__ gamma, const float* __restrict__ beta,
        const float* __restrict__ mean, const float* __restrict__ var,
        const float* __restrict__ Wn /* W1_1: 128x64 */) {
    constexpr int MT = 32, LD = 132;
    __shared__ float sh[MT * LD];
    const int tid = threadIdx.x, wave = tid >> 6, lane = tid & 63;
    const int nodeBase = blockIdx.x * MT;
    const uint4* x4 = (const uint4*)xh;   // row = 16 uint4 chunks (8 bf16 each)

    // ---- phase 1: bf16 gather, fp32 accumulate. C4=16 chunks, EPI=4 edges/inst ----
    const int chunk = lane & 15;
    const int esl   = lane >> 4;   // 0..3
    for (int r = wave; r < MT; r += 4) {
        int node = nodeBase + r;
        float a0=0,a1=0,a2=0,a3=0,a4=0,a5=0,a6=0,a7=0;
        #define ACC_U4(u) do { \
            a0 += BF2F_LO((u).x); a1 += BF2F_HI((u).x); \
            a2 += BF2F_LO((u).y); a3 += BF2F_HI((u).y); \
            a4 += BF2F_LO((u).z); a5 += BF2F_HI((u).z); \
            a6 += BF2F_LO((u).w); a7 += BF2F_HI((u).w); } while(0)
        if (node < NN) {
            if (esl == 0) { uint4 u = x4[(size_t)node * 16 + chunk]; ACC_U4(u); }
            int beg = rowptr[node], end = rowptr[node + 1];
            int cnt = end - beg;
            for (int c = 0; c < cnt; c += 64) {
                int take = min(64, cnt - c);
                int myi = (lane < take) ? esrc[beg + c + lane] : 0;
                int i = 0;
                for (; i + 16 <= take; i += 16) {
                    int s0 = __shfl(myi, i + esl);
                    int s1 = __shfl(myi, i + 4 + esl);
                    int s2 = __shfl(myi, i + 8 + esl);
                    int s3 = __shfl(myi, i + 12 + esl);
                    uint4 u0 = x4[(size_t)s0 * 16 + chunk];
                    uint4 u1 = x4[(size_t)s1 * 16 + chunk];
                    uint4 u2 = x4[(size_t)s2 * 16 + chunk];
                    uint4 u3 = x4[(size_t)s3 * 16 + chunk];
                    ACC_U4(u0); ACC_U4(u1); ACC_U4(u2); ACC_U4(u3);
                }
                for (; i + 4 <= take; i += 4) {
                    int s = __shfl(myi, i + esl);
                    uint4 u = x4[(size_t)s * 16 + chunk];
                    ACC_U4(u);
                }
                int rem = take - i;
                if (rem > 0) {
                    int s = __shfl(myi, i + ((esl < rem) ? esl : 0));
                    uint4 u = x4[(size_t)s * 16 + chunk];
                    if (esl < rem) ACC_U4(u);
                }
            }
        }
        #undef ACC_U4
        // butterfly over edge-slot bits (lane bits 4,5)
        #pragma unroll
        for (int off = 32; off >= 16; off >>= 1) {
            a0 += __shfl_xor(a0, off); a1 += __shfl_xor(a1, off);
            a2 += __shfl_xor(a2, off); a3 += __shfl_xor(a3, off);
            a4 += __shfl_xor(a4, off); a5 += __shfl_xor(a5, off);
            a6 += __shfl_xor(a6, off); a7 += __shfl_xor(a7, off);
        }
        if (lane < 16) {
            *(float4*)&sh[r * LD + chunk * 8]     = make_float4(a0, a1, a2, a3);
            *(float4*)&sh[r * LD + chunk * 8 + 4] = make_float4(a4, a5, a6, a7);
        }
    }
    __syncthreads();

    // GEMM1: 128->128, relu
    const int colid = tid % 32, rowid = tid / 32;      // CT=32, RT=8
    const int c0 = colid * 4, r0 = rowid * 4;          // RPT=4
    float acc[4][4];
    {
        float4 bv = *(const float4*)&b1[c0];
        #pragma unroll
        for (int i = 0; i < 4; i++) {
            acc[i][0] = bv.x; acc[i][1] = bv.y; acc[i][2] = bv.z; acc[i][3] = bv.w;
        }
        #pragma unroll 2
        for (int k4 = 0; k4 < 32; k4++) {
            float4 w[4];
            #pragma unroll
            for (int kk = 0; kk < 4; kk++)
                w[kk] = *(const float4*)&W1[(k4 * 4 + kk) * 128 + c0];
            #pragma unroll
            for (int i = 0; i < 4; i++) {
                float4 a = *(const float4*)&sh[(r0 + i) * LD + k4 * 4];
                const float av[4] = {a.x, a.y, a.z, a.w};
                #pragma unroll
                for (int kk = 0; kk < 4; kk++) {
                    const float* wp = (const float*)&w[kk];
                    #pragma unroll
                    for (int j = 0; j < 4; j++)
                        acc[i][j] = fmaf(av[kk], wp[j], acc[i][j]);
                }
            }
        }
    }
    __syncthreads();
    #pragma unroll
    for (int i = 0; i < 4; i++) {
        float4 h;
        h.x = fmaxf(acc[i][0], 0.f); h.y = fmaxf(acc[i][1], 0.f);
        h.z = fmaxf(acc[i][2], 0.f); h.w = fmaxf(acc[i][3], 0.f);
        *(float4*)&sh[(r0 + i) * LD + c0] = h;
    }
    __syncthreads();

    // GEMM2: 128->128, BN, relu
    {
        float4 bv = *(const float4*)&b2[c0];
        #pragma unroll
        for (int i = 0; i < 4; i++) {
            acc[i][0] = bv.x; acc[i][1] = bv.y; acc[i][2] = bv.z; acc[i][3] = bv.w;
        }
        #pragma unroll 2
        for (int k4 = 0; k4 < 32; k4++) {
            float4 w[4];
            #pragma unroll
            for (int kk = 0; kk < 4; kk++)
                w[kk] = *(const float4*)&W2[(k4 * 4 + kk) * 128 + c0];
            #pragma unroll
            for (int i = 0; i < 4; i++) {
                float4 a = *(const float4*)&sh[(r0 + i) * LD + k4 * 4];
                const float av[4] = {a.x, a.y, a.z, a.w};
                #pragma unroll
                for (int kk = 0; kk < 4; kk++) {
                    const float* wp = (const float*)&w[kk];
                    #pragma unroll
                    for (int j = 0; j < 4; j++)
                        acc[i][j] = fmaf(av[kk], wp[j], acc[i][j]);
                }
            }
        }
    }
    float4 gv = *(const float4*)&gamma[c0];
    float4 bev = *(const float4*)&beta[c0];
    float4 mv = *(const float4*)&mean[c0];
    float4 vv = *(const float4*)&var[c0];
    float scale[4], shift[4];
    {
        const float* gp = (const float*)&gv; const float* bp = (const float*)&bev;
        const float* mp = (const float*)&mv; const float* vp = (const float*)&vv;
        #pragma unroll
        for (int j = 0; j < 4; j++) {
            scale[j] = gp[j] * (1.0f / sqrtf(vp[j] + 1e-5f));
            shift[j] = bp[j] - mp[j] * scale[j];
        }
    }
    __syncthreads();
    #pragma unroll
    for (int i = 0; i < 4; i++) {
        float4 y;
        y.x = fmaxf(fmaf(acc[i][0], scale[0], shift[0]), 0.f);
        y.y = fmaxf(fmaf(acc[i][1], scale[1], shift[1]), 0.f);
        y.z = fmaxf(fmaf(acc[i][2], scale[2], shift[2]), 0.f);
        y.w = fmaxf(fmaf(acc[i][3], scale[3], shift[3]), 0.f);
        *(float4*)&sh[(r0 + i) * LD + c0] = y;
    }
    __syncthreads();

    // GEMM3: y(128) @ W1_1(128x64) -> z1
    {
        const int colid2 = tid % 16, rowid2 = tid / 16;   // CT=16, RT=16
        const int c0b = colid2 * 4, r0b = rowid2 * 2;     // RPT=2
        float a3[2][4] = {};
        #pragma unroll 2
        for (int k4 = 0; k4 < 32; k4++) {
            float4 w[4];
            #pragma unroll
            for (int kk = 0; kk < 4; kk++)
                w[kk] = *(const float4*)&Wn[(k4 * 4 + kk) * 64 + c0b];
            #pragma unroll
            for (int i = 0; i < 2; i++) {
                float4 a = *(const float4*)&sh[(r0b + i) * LD + k4 * 4];
                const float av[4] = {a.x, a.y, a.z, a.w};
                #pragma unroll
                for (int kk = 0; kk < 4; kk++) {
                    const float* wp = (const float*)&w[kk];
                    #pragma unroll
                    for (int j = 0; j < 4; j++)
                        a3[i][j] = fmaf(av[kk], wp[j], a3[i][j]);
                }
            }
        }
        #pragma unroll
        for (int i = 0; i < 2; i++) {
            int node = nodeBase + r0b + i;
            if (node < NN)
                *(float4*)&z1[(size_t)node * 64 + c0b] =
                    make_float4(a3[i][0], a3[i][1], a3[i][2], a3[i][3]);
        }
    }
}

// ---------- fused layer 1: gather z1(64) -> +b1,relu -> W2_1+BN+relu -> xW1_2 -> z2(N x 32) ----------
__global__ __launch_bounds__(256) void fused_L1(
        const float* __restrict__ z1in, const int* __restrict__ esrc,
        const int* __restrict__ rowptr, float* __restrict__ z2,
        const float* __restrict__ b1, const float* __restrict__ W2,
        const float* __restrict__ b2, const float* __restrict__ gamma,
        const float* __restrict__ beta, const float* __restrict__ mean,
        const float* __restrict__ var, const float* __restrict__ Wn /* W1_2: 64x32 */) {
    constexpr int MT = 32, LD = 68;
    __shared__ float sh[MT * LD];
    const int tid = threadIdx.x, wave = tid >> 6, lane = tid & 63;
    const int nodeBase = blockIdx.x * MT;

    for (int r = wave; r < MT; r += 4) {
        int node = nodeBase + r;
        float4 acc = make_float4(0.f, 0.f, 0.f, 0.f);
        if (node < NN) {
            int beg = rowptr[node], end = rowptr[node + 1];
            acc = gather_node<64>((const float4*)z1in, esrc, beg, end - beg, node, lane);
        }
        if (lane < 16) {
            float4 bv = *(const float4*)&b1[lane * 4];
            float4 h;
            h.x = fmaxf(acc.x + bv.x, 0.f); h.y = fmaxf(acc.y + bv.y, 0.f);
            h.z = fmaxf(acc.z + bv.z, 0.f); h.w = fmaxf(acc.w + bv.w, 0.f);
            *(float4*)&sh[r * LD + lane * 4] = h;
        }
    }
    __syncthreads();

    const int colid = tid % 16, rowid = tid / 16;  // CT=16, RT=16
    const int c0 = colid * 4, r0 = rowid * 2;      // RPT=2
    float acc[2][4];
    {
        float4 bv = *(const float4*)&b2[c0];
        #pragma unroll
        for (int i = 0; i < 2; i++) {
            acc[i][0] = bv.x; acc[i][1] = bv.y; acc[i][2] = bv.z; acc[i][3] = bv.w;
        }
        #pragma unroll 2
        for (int k4 = 0; k4 < 16; k4++) {
            float4 w[4];
            #pragma unroll
            for (int kk = 0; kk < 4; kk++)
                w[kk] = *(const float4*)&W2[(k4 * 4 + kk) * 64 + c0];
            #pragma unroll
            for (int i = 0; i < 2; i++) {
                float4 a = *(const float4*)&sh[(r0 + i) * LD + k4 * 4];
                const float av[4] = {a.x, a.y, a.z, a.w};
                #pragma unroll
                for (int kk = 0; kk < 4; kk++) {
                    const float* wp = (const float*)&w[kk];
                    #pragma unroll
                    for (int j = 0; j < 4; j++)
                        acc[i][j] = fmaf(av[kk], wp[j], acc[i][j]);
                }
            }
        }
    }
    float4 gv = *(const float4*)&gamma[c0];
    float4 bev = *(const float4*)&beta[c0];
    float4 mv = *(const float4*)&mean[c0];
    float4 vv = *(const float4*)&var[c0];
    float scale[4], shift[4];
    {
        const float* gp = (const float*)&gv; const float* bp = (const float*)&bev;
        const float* mp = (const float*)&mv; const float* vp = (const float*)&vv;
        #pragma unroll
        for (int j = 0; j < 4; j++) {
            scale[j] = gp[j] * (1.0f / sqrtf(vp[j] + 1e-5f));
            shift[j] = bp[j] - mp[j] * scale[j];
        }
    }
    __syncthreads();
    #pragma unroll
    for (int i = 0; i < 2; i++) {
        float4 y;
        y.x = fmaxf(fmaf(acc[i][0], scale[0], shift[0]), 0.f);
        y.y = fmaxf(fmaf(acc[i][1], scale[1], shift[1]), 0.f);
        y.z = fmaxf(fmaf(acc[i][2], scale[2], shift[2]), 0.f);
        y.w = fmaxf(fmaf(acc[i][3], scale[3], shift[3]), 0.f);
        *(float4*)&sh[(r0 + i) * LD + c0] = y;
    }
    __syncthreads();

    {
        const int colid2 = tid % 8, rowid2 = tid / 8;   // CT=8, RT=32, RPT=1
        const int c0b = colid2 * 4, r0b = rowid2;
        float a3[4] = {};
        #pragma unroll 2
        for (int k4 = 0; k4 < 16; k4++) {
            float4 w[4];
            #pragma unroll
            for (int kk = 0; kk < 4; kk++)
                w[kk] = *(const float4*)&Wn[(k4 * 4 + kk) * 32 + c0b];
            float4 a = *(const float4*)&sh[r0b * LD + k4 * 4];
            const float av[4] = {a.x, a.y, a.z, a.w};
            #pragma unroll
            for (int kk = 0; kk < 4; kk++) {
                const float* wp = (const float*)&w[kk];
                #pragma unroll
                for (int j = 0; j < 4; j++)
                    a3[j] = fmaf(av[kk], wp[j], a3[j]);
            }
        }
        int node = nodeBase + r0b;
        if (node < NN)
            *(float4*)&z2[(size_t)node * 32 + c0b] =
                make_float4(a3[0], a3[1], a3[2], a3[3]);
    }
}

// ---------- fused layer 2: gather z2(32) -> +b1,relu -> W2_2+BN -> xW_lin -> logits(N) ----------
__global__ __launch_bounds__(256) void fused_L2(
        const float* __restrict__ z2in, const int* __restrict__ esrc,
        const int* __restrict__ rowptr, float* __restrict__ logits,
        const float* __restrict__ b1, const float* __restrict__ W2,
        const float* __restrict__ b2, const float* __restrict__ gamma,
        const float* __restrict__ beta, const float* __restrict__ mean,
        const float* __restrict__ var, const float* __restrict__ Wl,
        const float* __restrict__ bl) {
    constexpr int MT = 32, LD = 36;
    __shared__ float sh[MT * LD];
    const int tid = threadIdx.x, wave = tid >> 6, lane = tid & 63;
    const int nodeBase = blockIdx.x * MT;

    for (int r = wave; r < MT; r += 4) {
        int node = nodeBase + r;
        float4 acc = make_float4(0.f, 0.f, 0.f, 0.f);
        if (node < NN) {
            int beg = rowptr[node], end = rowptr[node + 1];
            acc = gather_node<32>((const float4*)z2in, esrc, beg, end - beg, node, lane);
        }
        if (lane < 8) {
            float4 bv = *(const float4*)&b1[lane * 4];
            float4 h;
            h.x = fmaxf(acc.x + bv.x, 0.f); h.y = fmaxf(acc.y + bv.y, 0.f);
            h.z = fmaxf(acc.z + bv.z, 0.f); h.w = fmaxf(acc.w + bv.w, 0.f);
            *(float4*)&sh[r * LD + lane * 4] = h;
        }
    }
    __syncthreads();

    const int colid = tid % 8, rowid = tid / 8;   // CT=8, RT=32, RPT=1
    const int c0 = colid * 4, r0 = rowid;
    float acc[4];
    {
        float4 bv = *(const float4*)&b2[c0];
        acc[0] = bv.x; acc[1] = bv.y; acc[2] = bv.z; acc[3] = bv.w;
        #pragma unroll
        for (int k4 = 0; k4 < 8; k4++) {
            float4 w[4];
            #pragma unroll
            for (int kk = 0; kk < 4; kk++)
                w[kk] = *(const float4*)&W2[(k4 * 4 + kk) * 32 + c0];
            float4 a = *(const float4*)&sh[r0 * LD + k4 * 4];
            const float av[4] = {a.x, a.y, a.z, a.w};
            #pragma unroll
            for (int kk = 0; kk < 4; kk++) {
                const float* wp = (const float*)&w[kk];
                #pragma unroll
                for (int j = 0; j < 4; j++)
                    acc[j] = fmaf(av[kk], wp[j], acc[j]);
            }
        }
    }
    float4 gv = *(const float4*)&gamma[c0];
    float4 bev = *(const float4*)&beta[c0];
    float4 mv = *(const float4*)&mean[c0];
    float4 vv = *(const float4*)&var[c0];
    float4 wl = *(const float4*)&Wl[c0];
    float p = 0.f;
    {
        const float* gp = (const float*)&gv; const float* bp = (const float*)&bev;
        const float* mp = (const float*)&mv; const float* vp = (const float*)&vv;
        const float* wp = (const float*)&wl;
        #pragma unroll
        for (int j = 0; j < 4; j++) {
            float sc = gp[j] * (1.0f / sqrtf(vp[j] + 1e-5f));
            float y = (acc[j] - mp[j]) * sc + bp[j];
            p = fmaf(y, wp[j], p);
        }
    }
    p += __shfl_xor(p, 1);
    p += __shfl_xor(p, 2);
    p += __shfl_xor(p, 4);
    int node = nodeBase + r0;
    if ((tid & 7) == 0 && node < NN)
        logits[node] = (p + bl[0]) * 0.2f;
}

// ---------- head ----------
__global__ void find_bounds(const int* __restrict__ batch, int* __restrict__ gstart) {
    int n = blockIdx.x * 256 + threadIdx.x;
    if (n >= NN) return;
    int b = batch[n];
    if (n == 0) {
        for (int g = 0; g <= b; g++) gstart[g] = 0;
    } else {
        int p = batch[n - 1];
        for (int g = p + 1; g <= b; g++) gstart[g] = n;
    }
    if (n == NN - 1) {
        for (int g = b + 1; g <= NG; g++) gstart[g] = NN;
    }
}

__global__ __launch_bounds__(256) void seg_softmax(
        const float* __restrict__ logits, const int* __restrict__ gstart,
        float* __restrict__ out) {
    __shared__ float slog[1024];
    __shared__ float sred[4];
    __shared__ float sbc[2];
    int g = blockIdx.x;
    int beg = gstart[g], end = gstart[g + 1];
    int cnt = end - beg;
    int t = threadIdx.x;
    if (cnt <= 0) return;
    bool fits = (cnt <= 1024);

    float lmax = -3.402823466e+38f;
    for (int i = t; i < cnt; i += 256) {
        float lg = logits[beg + i];
        if (fits) slog[i] = lg;
        lmax = fmaxf(lmax, lg);
    }
    #pragma unroll
    for (int off = 32; off > 0; off >>= 1)
        lmax = fmaxf(lmax, __shfl_down(lmax, off));
    if ((t & 63) == 0) sred[t >> 6] = lmax;
    __syncthreads();
    if (t == 0) sbc[0] = fmaxf(fmaxf(sred[0], sred[1]), fmaxf(sred[2], sred[3]));
    __syncthreads();
    float gm = sbc[0];

    float lsum = 0.f;
    for (int i = t; i < cnt; i += 256) {
        float lg = fits ? slog[i] : logits[beg + i];
        float e = expf(lg - gm);
        if (fits) slog[i] = e;
        lsum += e;
    }
    #pragma unroll
    for (int off = 32; off > 0; off >>= 1)
        lsum += __shfl_down(lsum, off);
    __syncthreads();
    if ((t & 63) == 0) sred[t >> 6] = lsum;
    __syncthreads();
    if (t == 0) sbc[1] = (sred[0] + sred[1]) + (sred[2] + sred[3]);
    __syncthreads();
    float inv = 1.0f / sbc[1];

    for (int i = t; i < cnt; i += 256) {
        float e = fits ? slog[i] : expf(logits[beg + i] - gm);
        out[beg + i] = e * inv;
    }
}

// ---------- launch ----------
extern "C" void kernel_launch(void* const* d_in, const int* in_sizes, int n_in,
                              void* d_out, int out_size, void* d_ws, size_t ws_size,
                              hipStream_t stream) {
    const float* x    = (const float*)d_in[0];
    const int*   ei   = (const int*)d_in[1];
    const int*   srcI = ei;
    const int*   dstI = ei + NE;
    const int*   batch = (const int*)d_in[2];

    const float* P[29];
    for (int i = 0; i < 29; i++) P[i] = (const float*)d_in[i];
    const float* Wlin = P[27];
    const float* blin = P[28];

    unsigned short* xh = (unsigned short*)d_ws;     // N x 128 bf16 (16B-aligned)
    float* z1     = (float*)(xh + (size_t)NN * 128); // N x 64
    float* z2     = z1 + (size_t)NN * 64;            // N x 32
    float* logits = z2 + (size_t)NN * 32;            // N
    int* gstart = (int*)(logits + NN);               // NG+1
    int* deg    = gstart + NG + 1;                   // N
    int* iscan  = deg + NN;                          // N
    int* rowptr = iscan + NN;                        // N+1
    int* cur    = rowptr + NN + 1;                   // N
    int* bsum   = cur + NN;                          // NB
    int* boff   = bsum + NB;                         // NB
    int* esrc   = boff + NB;                         // E
    float* outp = (float*)d_out;

    const int TB = 256;

    // ---- convert x to bf16 (overlaps nothing; cheap) ----
    {
        int n4 = NN * 128 / 4;
        x_to_bf16<<<(n4 + TB - 1) / TB, TB, 0, stream>>>(
            (const float4*)x, (ushort4*)xh, n4);
    }

    // ---- build CSR ----
    hipMemsetAsync(deg, 0, NN * sizeof(int), stream);
    hist_deg<<<(NE + TB - 1) / TB, TB, 0, stream>>>(dstI, deg);
    block_scan<<<NB, 256, 0, stream>>>(deg, iscan, bsum);
    scan_bsum<<<1, 256, 0, stream>>>(bsum, boff);
    finalize_rowptr<<<NB, 256, 0, stream>>>(deg, iscan, boff, rowptr, cur);
    fill_csr<<<(NE + TB - 1) / TB, TB, 0, stream>>>(srcI, dstI, cur, esrc);

    find_bounds<<<NB, 256, 0, stream>>>(batch, gstart);

    const int FB = (NN + 31) / 32;

    fused_L0<<<FB, 256, 0, stream>>>(xh, esrc, rowptr, z1,
        P[3], P[4], P[5], P[6], P[7], P[8], P[9], P[10], P[11]);
    fused_L1<<<FB, 256, 0, stream>>>(z1, esrc, rowptr, z2,
        P[12], P[13], P[14], P[15], P[16], P[17], P[18], P[19]);
    fused_L2<<<FB, 256, 0, stream>>>(z2, esrc, rowptr, logits,
        P[20], P[21], P[22], P[23], P[24], P[25], P[26], Wlin, blin);

    seg_softmax<<<NG, 256, 0, stream>>>(logits, gstart, outp);
}